// Round 3
// baseline (1032.249 us; speedup 1.0000x reference)
//
#include <hip/hip_runtime.h>
#include <math.h>

typedef unsigned short u16;
typedef __attribute__((ext_vector_type(8))) short short8;
typedef __attribute__((ext_vector_type(4))) float floatx4;
typedef __attribute__((ext_vector_type(4))) unsigned short ushort4v;

#define DEV static __device__ __forceinline__

DEV u16 f2b(float f) {
  unsigned u = __builtin_bit_cast(unsigned, f);
  u += 0x7fffu + ((u >> 16) & 1u);
  return (u16)(u >> 16);
}
DEV float b2f(u16 h) { return __builtin_bit_cast(float, ((unsigned)h) << 16); }

DEV void gld16(const u16* g, u16* l) {
  __builtin_amdgcn_global_load_lds((__attribute__((address_space(1))) void*)(g),
                                   (__attribute__((address_space(3))) void*)(l), 16, 0, 0);
}

// ---------------- K1: token-shift mixes -> 6 bf16 tensors ----------------
__global__ __launch_bounds__(256) void ew_mix(
    const float* __restrict__ x,
    const float* __restrict__ cr, const float* __restrict__ ck,
    const float* __restrict__ cv, const float* __restrict__ cw,
    const float* __restrict__ ca, const float* __restrict__ cg,
    u16* __restrict__ oxr, u16* __restrict__ oxk, u16* __restrict__ oxv,
    u16* __restrict__ oxw, u16* __restrict__ oxa, u16* __restrict__ oxg)
{
  const long idx = (long)blockIdx.x * 256 + threadIdx.x;
  const long row = idx >> 9;
  const int c4 = (int)(idx & 511) << 2;
  const long off = (row << 11) + c4;
  const float4 xc = *(const float4*)(x + off);
  float4 xp = make_float4(0.f, 0.f, 0.f, 0.f);
  if ((row & 4095) != 0) xp = *(const float4*)(x + off - 2048);
  const float xx0 = xp.x - xc.x, xx1 = xp.y - xc.y, xx2 = xp.z - xc.z, xx3 = xp.w - xc.w;
#define EMIT(cp, op) { const float4 cf = *(const float4*)(cp + c4);            \
    ushort4v o = { f2b(xc.x + xx0*cf.x), f2b(xc.y + xx1*cf.y),                 \
                   f2b(xc.z + xx2*cf.z), f2b(xc.w + xx3*cf.w) };               \
    *(ushort4v*)(op + off) = o; }
  EMIT(cr, oxr); EMIT(ck, oxk); EMIT(cv, oxv);
  EMIT(cw, oxw); EMIT(ca, oxa); EMIT(cg, oxg);
#undef EMIT
}

// ---------------- K2: cast 4 big square weights f32 -> bf16 ----------------
__global__ __launch_bounds__(256) void cast_w4(
    const float* __restrict__ s0, const float* __restrict__ s1,
    const float* __restrict__ s2, const float* __restrict__ s3,
    u16* __restrict__ d0, u16* __restrict__ d1, u16* __restrict__ d2, u16* __restrict__ d3)
{
  const float* s; u16* d;
  switch (blockIdx.y) {
    case 0: s = s0; d = d0; break;
    case 1: s = s1; d = d1; break;
    case 2: s = s2; d = d2; break;
    default: s = s3; d = d3; break;
  }
  const long i = ((long)blockIdx.x * 256 + threadIdx.x) * 8;
  const float4 a = *(const float4*)(s + i);
  const float4 b = *(const float4*)(s + i + 4);
  ushort4v lo = { f2b(a.x), f2b(a.y), f2b(a.z), f2b(a.w) };
  ushort4v hi = { f2b(b.x), f2b(b.y), f2b(b.z), f2b(b.w) };
  *(ushort4v*)(d + i) = lo;
  *(ushort4v*)(d + i + 4) = hi;
}

// ---------------- K3: transpose (+zero-pad) LoRA weights -> bf16 [N][K] ----------------
struct TJobs {
  const float* src[8]; u16* dst[8];
  int src_k[8], src_n[8], dst_n[8], dst_k[8];
};
__global__ __launch_bounds__(256) void transpose_small(TJobs j)
{
  const int w = blockIdx.y;   // wave-uniform, constant-per-block index
  const long idx = (long)blockIdx.x * 256 + threadIdx.x;
  // constant-index loads per case to avoid scratch (rule #20)
  const float* src; u16* dst; int sk, sn, dn, dk;
  switch (w) {
    case 0: src=j.src[0]; dst=j.dst[0]; sk=j.src_k[0]; sn=j.src_n[0]; dn=j.dst_n[0]; dk=j.dst_k[0]; break;
    case 1: src=j.src[1]; dst=j.dst[1]; sk=j.src_k[1]; sn=j.src_n[1]; dn=j.dst_n[1]; dk=j.dst_k[1]; break;
    case 2: src=j.src[2]; dst=j.dst[2]; sk=j.src_k[2]; sn=j.src_n[2]; dn=j.dst_n[2]; dk=j.dst_k[2]; break;
    case 3: src=j.src[3]; dst=j.dst[3]; sk=j.src_k[3]; sn=j.src_n[3]; dn=j.dst_n[3]; dk=j.dst_k[3]; break;
    case 4: src=j.src[4]; dst=j.dst[4]; sk=j.src_k[4]; sn=j.src_n[4]; dn=j.dst_n[4]; dk=j.dst_k[4]; break;
    case 5: src=j.src[5]; dst=j.dst[5]; sk=j.src_k[5]; sn=j.src_n[5]; dn=j.dst_n[5]; dk=j.dst_k[5]; break;
    case 6: src=j.src[6]; dst=j.dst[6]; sk=j.src_k[6]; sn=j.src_n[6]; dn=j.dst_n[6]; dk=j.dst_k[6]; break;
    default:src=j.src[7]; dst=j.dst[7]; sk=j.src_k[7]; sn=j.src_n[7]; dn=j.dst_n[7]; dk=j.dst_k[7]; break;
  }
  const long total = (long)dn * dk;
  if (idx >= total) return;
  const int n = (int)(idx / dk), k = (int)(idx % dk);
  float v = 0.f;
  if (k < sk && n < sn) v = src[(long)k * sn + n];
  dst[idx] = f2b(v);
}

// ---------------- GEMM 128x128 (m97 structure), job-table ----------------
// ops: 1=bf16  2=tanh->bf16  3=sig->bf16  4=w-f32(+bias)  5=sig-f32(+bias)  6=sig-bf16(+bias)
struct J128 { const u16* A; const u16* B; void* C; const float* bias; int N, K, lda, op, b0; };
struct J128v { J128 j[4]; };

__global__ __launch_bounds__(256, 2) void gemm128(J128v jv)
{
  __shared__ __align__(16) u16 sA[128 * 64];
  __shared__ __align__(16) u16 sB[128 * 64];
  const int bid = blockIdx.x;
  int jid = 0;
#pragma unroll
  for (int q = 1; q < 4; ++q) if (bid >= jv.j[q].b0) jid = q;
  // wave-uniform switch with CONSTANT indices — keeps table in SGPRs, no scratch
  J128 J;
  switch (jid) {
    case 0: J = jv.j[0]; break;
    case 1: J = jv.j[1]; break;
    case 2: J = jv.j[2]; break;
    default: J = jv.j[3]; break;
  }
  const int lb = bid - J.b0;
  const int tid = threadIdx.x;
  const int wave = tid >> 6, lane = tid & 63;
  const int lrow = lane & 15, lkg = lane >> 4;
  const int wm = wave >> 1, wn = wave & 1;
  const int nbn = J.N >> 7;
  const int bm = lb / nbn, bn = lb % nbn;

  const u16* Abase = J.A + (long)bm * 128 * J.lda;
  const u16* Bbase = J.B + (long)bn * 128 * J.K;

  floatx4 acc[4][4];
#pragma unroll
  for (int i = 0; i < 4; ++i)
#pragma unroll
    for (int jq = 0; jq < 4; ++jq) acc[i][jq] = (floatx4)0.f;

  const int nK = J.K >> 6;
  for (int kt = 0; kt < nK; ++kt) {
    const int k0 = kt << 6;
    __syncthreads();
#pragma unroll
    for (int i = 0; i < 4; ++i) {
      const int c = i * 256 + tid;
      const int row = c >> 3;
      const int sch = (c & 7) ^ (row & 7);
      const long goffA = (long)row * J.lda + k0 + sch * 8;
      const long goffB = (long)row * J.K + k0 + sch * 8;
      const int lbase = (i * 256 + wave * 64) * 8;
      gld16(Abase + goffA, &sA[lbase]);
      gld16(Bbase + goffB, &sB[lbase]);
    }
    asm volatile("s_waitcnt vmcnt(0)" ::: "memory");
    __syncthreads();
#pragma unroll
    for (int ks = 0; ks < 2; ++ks) {
      short8 af[4], bfr[4];
#pragma unroll
      for (int mi = 0; mi < 4; ++mi) {
        const int row = wm * 64 + mi * 16 + lrow;
        const int ch = (ks * 4 + lkg) ^ (row & 7);
        af[mi] = *(const short8*)&sA[row * 64 + ch * 8];
      }
#pragma unroll
      for (int ni = 0; ni < 4; ++ni) {
        const int row = wn * 64 + ni * 16 + lrow;
        const int ch = (ks * 4 + lkg) ^ (row & 7);
        bfr[ni] = *(const short8*)&sB[row * 64 + ch * 8];
      }
#pragma unroll
      for (int mi = 0; mi < 4; ++mi)
#pragma unroll
        for (int ni = 0; ni < 4; ++ni)
          acc[mi][ni] = __builtin_amdgcn_mfma_f32_16x16x32_bf16(af[mi], bfr[ni], acc[mi][ni], 0, 0, 0);
    }
  }

  const int row0 = bm * 128 + wm * 64 + lkg * 4;
  const int col0 = bn * 128 + wn * 64 + lrow;
  const int op = J.op;
#pragma unroll
  for (int mi = 0; mi < 4; ++mi) {
#pragma unroll
    for (int ni = 0; ni < 4; ++ni) {
      const int col = col0 + ni * 16;
#pragma unroll
      for (int r = 0; r < 4; ++r) {
        const long o = (long)(row0 + mi * 16 + r) * J.N + col;
        const float v = acc[mi][ni][r];
        if (op == 1) ((u16*)J.C)[o] = f2b(v);
        else if (op == 2) ((u16*)J.C)[o] = f2b(tanhf(v));
        else if (op == 3) ((u16*)J.C)[o] = f2b(1.f / (1.f + expf(-v)));
        else if (op == 4) {
          const float zz = -(v + J.bias[col]);
          const float sp = fmaxf(zz, 0.f) + log1pf(expf(-fabsf(zz)));
          ((float*)J.C)[o] = -sp - 0.5f;
        } else if (op == 5) {
          ((float*)J.C)[o] = 1.f / (1.f + expf(-(v + J.bias[col])));
        } else {  // 6
          ((u16*)J.C)[o] = f2b(1.f / (1.f + expf(-(v + J.bias[col]))));
        }
      }
    }
  }
}

// ---------------- GEMM 256x256 deep-pipelined (8-phase, counted vmcnt) ----------------
// Fixed M=8192, N=2048, K=2048 per job. C = A @ B^T, bf16 in.
struct G256 { const u16* A[3]; const u16* B[3]; void* C[3]; };

template<int OP>  // 0=f32 out, 1=bf16 out
__global__ __launch_bounds__(512, 2) void gemm256(G256 g)
{
  __shared__ __align__(16) u16 lds[8 * 8192];
  const int tid = threadIdx.x;
  const int wave = tid >> 6, lane = tid & 63;
  const int lrow = lane & 15, lq = lane >> 4;
  const int wm = wave >> 2, wn = wave & 3;
  const int job = blockIdx.x >> 8;
  const int lb = blockIdx.x & 255;
  const int bm = lb >> 3, bn = lb & 7;

  // constant-index job select (no scratch)
  const u16* Aj; const u16* Bj; void* Cj;
  switch (job) {
    case 0: Aj = g.A[0]; Bj = g.B[0]; Cj = g.C[0]; break;
    case 1: Aj = g.A[1]; Bj = g.B[1]; Cj = g.C[1]; break;
    default: Aj = g.A[2]; Bj = g.B[2]; Cj = g.C[2]; break;
  }
  const u16* __restrict__ Ab = Aj + (long)bm * 256 * 2048;
  const u16* __restrict__ Bb = Bj + (long)bn * 256 * 2048;

  int srco[2], dsto[2];
#pragma unroll
  for (int l = 0; l < 2; ++l) {
    const int c = l * 512 + tid;
    const int row = c >> 2, q = c & 3;
    const int qs = q ^ ((row >> 1) & 3);
    srco[l] = row * 2048 + qs * 8;
    dsto[l] = (l * 512 + wave * 64) * 8;
  }
  int offA[2][4], offB[4];
#pragma unroll
  for (int qm = 0; qm < 2; ++qm)
#pragma unroll
    for (int mi = 0; mi < 4; ++mi) {
      const int r = wm * 128 + qm * 64 + mi * 16 + lrow;
      offA[qm][mi] = r * 32 + (lq ^ ((r >> 1) & 3)) * 8;
    }
#pragma unroll
  for (int ni = 0; ni < 4; ++ni) {
    const int r = wn * 64 + ni * 16 + lrow;
    offB[ni] = r * 32 + (lq ^ ((r >> 1) & 3)) * 8;
  }

  floatx4 acc[8][4];
#pragma unroll
  for (int i = 0; i < 8; ++i)
#pragma unroll
    for (int jq = 0; jq < 4; ++jq) acc[i][jq] = (floatx4)0.f;

#define STAGE(sU, slot) {                                                  \
    const int t_ = (sU) >> 2, j_ = (sU) & 3;                               \
    const u16* base_ = (j_ & 1) ? Bb : Ab;                                 \
    const int kofs_ = t_ * 64 + ((j_ & 2) ? 32 : 0);                       \
    gld16(base_ + srco[0] + kofs_, &lds[(slot) * 8192 + dsto[0]]);         \
    gld16(base_ + srco[1] + kofs_, &lds[(slot) * 8192 + dsto[1]]);         \
  }

#pragma unroll
  for (int s = 0; s < 6; ++s) STAGE(s, s);
  asm volatile("s_waitcnt vmcnt(4)" ::: "memory");
  asm volatile("s_barrier" ::: "memory");

  const int nT = 32;
  for (int te = 0; te < nT; te += 2) {
#pragma unroll
    for (int ph = 0; ph < 8; ++ph) {
      const int ks = (ph >> 1) & 1, qm = ph & 1;
      const int slotA = (ph & 4) ? (4 + 2 * ks) : (2 * ks);
      const int slotB = slotA + 1;
      short8 af[4], bf[4];
#pragma unroll
      for (int mi = 0; mi < 4; ++mi)
        af[mi] = *(const short8*)&lds[slotA * 8192 + offA[qm][mi]];
#pragma unroll
      for (int ni = 0; ni < 4; ++ni)
        bf[ni] = *(const short8*)&lds[slotB * 8192 + offB[ni]];
      const int sU = 4 * te + 6 + ph;
      if (sU < 4 * nT) { STAGE(sU, (6 + ph) & 7); }
      if ((ph & 3) == 3) asm volatile("s_waitcnt vmcnt(4)" ::: "memory");
      asm volatile("s_barrier" ::: "memory");
      __builtin_amdgcn_s_setprio(1);
      const int am = qm * 4;
#pragma unroll
      for (int mi = 0; mi < 4; ++mi)
#pragma unroll
        for (int ni = 0; ni < 4; ++ni)
          acc[am + mi][ni] = __builtin_amdgcn_mfma_f32_16x16x32_bf16(af[mi], bf[ni], acc[am + mi][ni], 0, 0, 0);
      __builtin_amdgcn_s_setprio(0);
      asm volatile("s_barrier" ::: "memory");
    }
  }
#undef STAGE

  const long row0 = (long)bm * 256 + wm * 128 + lq * 4;
  const int col0 = bn * 256 + wn * 64 + lrow;
#pragma unroll
  for (int mi = 0; mi < 8; ++mi) {
#pragma unroll
    for (int ni = 0; ni < 4; ++ni) {
      const int col = col0 + ni * 16;
#pragma unroll
      for (int r = 0; r < 4; ++r) {
        const long o = (row0 + mi * 16 + r) * 2048 + col;
        const float v = acc[mi][ni][r];
        if constexpr (OP == 0) ((float*)Cj)[o] = v;
        else ((u16*)Cj)[o] = f2b(v);
      }
    }
  }
}

// ---------------- K6: per-head fused epilogue ----------------
DEV float wsum64(float v) {
  v += __shfl_xor(v, 1);  v += __shfl_xor(v, 2);  v += __shfl_xor(v, 4);
  v += __shfl_xor(v, 8);  v += __shfl_xor(v, 16); v += __shfl_xor(v, 32);
  return v;
}

__global__ __launch_bounds__(256) void ew_head(
    const u16* __restrict__ r16, const u16* __restrict__ k16,
    float* __restrict__ kkout,
    const float* __restrict__ abuf,
    const u16* __restrict__ v0buf, const u16* __restrict__ vsbuf,
    const u16* __restrict__ gbuf,
    const float* __restrict__ y, const float* __restrict__ vfirst,
    const float* __restrict__ kkc, const float* __restrict__ kac,
    const float* __restrict__ rk, const float* __restrict__ lng,
    const float* __restrict__ lnb, u16* __restrict__ z)
{
  const int tid = threadIdx.x;
  const int wave = tid >> 6, lane = tid & 63;
  const long gh = (long)blockIdx.x * 4 + wave;
  const long m = gh >> 5;
  const int h = (int)(gh & 31);
  const int c = h * 64 + lane;
  const long off = (m << 11) + c;

  const float k0 = b2f(k16[off]);
  const float av = abuf[off];
  const float kf = k0 * (1.f + (av - 1.f) * kac[c]);
  const float kkr = k0 * kkc[c];
  const float nrm = sqrtf(wsum64(kkr * kkr));
  kkout[off] = kkr / fmaxf(nrm, 1e-12f);

  const float yv = y[off];
  const float mu = wsum64(yv) * 0.015625f;
  const float dy = yv - mu;
  const float var = wsum64(dy * dy) * 0.015625f;
  const float yn = dy * rsqrtf(var + 0.00064f) * lng[c] + lnb[c];

  const float dot = wsum64(b2f(r16[off]) * kf * rk[c]);

  const float v0v = b2f(v0buf[off]);
  const float sv = b2f(vsbuf[off]);
  const float vv = v0v + (vfirst[off] - v0v) * sv;

  const float y2 = yn + dot * vv;
  z[off] = f2b(y2 * b2f(gbuf[off]));
}

// ---------------- launch ----------------
extern "C" void kernel_launch(void* const* d_in, const int* in_sizes, int n_in,
                              void* d_out, int out_size, void* d_ws, size_t ws_size,
                              hipStream_t stream)
{
  (void)in_sizes; (void)out_size;
  if (n_in < 29) return;
  const int Mrows = 8192;
  const long C = 2048;
  const long MB_ = (long)Mrows * C;

  const float* x   = (const float*)d_in[0];
  const float* vf  = (const float*)d_in[1];
  const float* y   = (const float*)d_in[2];
  const float* x_r = (const float*)d_in[3];
  const float* x_w = (const float*)d_in[4];
  const float* x_k = (const float*)d_in[5];
  const float* x_v = (const float*)d_in[6];
  const float* x_a = (const float*)d_in[7];
  const float* x_g = (const float*)d_in[8];
  const float* w0  = (const float*)d_in[9];
  const float* w1  = (const float*)d_in[10];
  const float* w2  = (const float*)d_in[11];
  const float* a0  = (const float*)d_in[12];
  const float* a1  = (const float*)d_in[13];
  const float* a2  = (const float*)d_in[14];
  const float* v0  = (const float*)d_in[15];
  const float* v1  = (const float*)d_in[16];
  const float* v2  = (const float*)d_in[17];
  const float* g1  = (const float*)d_in[18];
  const float* g2  = (const float*)d_in[19];
  const float* k_k = (const float*)d_in[20];
  const float* k_a = (const float*)d_in[21];
  const float* r_k = (const float*)d_in[22];
  const float* W_r = (const float*)d_in[23];
  const float* W_k = (const float*)d_in[24];
  const float* W_v = (const float*)d_in[25];
  const float* W_o = (const float*)d_in[26];
  const float* lng = (const float*)d_in[27];
  const float* lnb = (const float*)d_in[28];

  float* out_sec = (float*)d_out;
  float* w_sec   = out_sec + MB_;
  float* a_sec   = w_sec + MB_;
  float* kk_sec  = a_sec + MB_;

  u16* k16 = (u16*)out_sec;            // dead d_out regions until final GEMM
  u16* r16 = (u16*)out_sec + MB_;
  u16* Wr16 = (u16*)w_sec;             // weight casts; dead before stage-2 writes w_sec
  u16* Wk16 = Wr16 + C * C;
  u16* Wv16 = Wk16 + C * C;

  u16* p = (u16*)d_ws;
  u16* xr = p;            p += MB_;
  u16* xk = p;            p += MB_;   // later z
  u16* xv = p;            p += MB_;
  u16* xw = p;            p += MB_;   // later vs
  u16* xa = p;            p += MB_;   // later g
  u16* xg = p;            p += MB_;   // later v0
  u16* Wo16 = p;          p += C * C;
  u16* w1T = p;           p += 128 * C;
  u16* a1T = p;           p += 128 * C;
  u16* v1T = p;           p += 128 * C;
  u16* g1T = p;           p += 256 * C;
  u16* w2T = p;           p += C * 128;
  u16* a2T = p;           p += C * 128;
  u16* v2T = p;           p += C * 128;
  u16* g2T = p;           p += C * 256;
  u16* hw  = p;           p += (long)Mrows * 128;
  u16* ha  = p;           p += (long)Mrows * 128;
  u16* hv  = p;           p += (long)Mrows * 128;
  u16* hg  = p;           p += (long)Mrows * 256;
  const size_t need = (size_t)((char*)p - (char*)d_ws);
  if (ws_size < need) return;

  u16* v0buf = xg;   // xg dead after stage-1 launch; enables merged r/k/v GEMM
  u16* zbuf  = xk;   // xk dead after merged GEMM reads it
  u16* vsbuf = xw;   // xw dead after stage-1
  u16* gbuf  = xa;   // xa dead after stage-1

  // 1: mixes
  ew_mix<<<16384, 256, 0, stream>>>(x, x_r, x_k, x_v, x_w, x_a, x_g,
                                    xr, xk, xv, xw, xa, xg);
  // 2: big weight casts
  cast_w4<<<dim3(2048, 4), 256, 0, stream>>>(W_r, W_k, W_v, W_o, Wr16, Wk16, Wv16, Wo16);
  // 3: LoRA weight transposes (+zero pad)
  TJobs tj;
  {
    const float* s_[8] = { w1, a1, v1, g1, w2, a2, v2, g2 };
    u16* d_[8]         = { w1T, a1T, v1T, g1T, w2T, a2T, v2T, g2T };
    const int sk_[8]   = { 2048, 2048, 2048, 2048, 128, 128, 64, 224 };
    const int sn_[8]   = { 128, 128, 64, 224, 2048, 2048, 2048, 2048 };
    const int dn_[8]   = { 128, 128, 128, 256, 2048, 2048, 2048, 2048 };
    const int dk_[8]   = { 2048, 2048, 2048, 2048, 128, 128, 128, 256 };
    for (int i = 0; i < 8; ++i) {
      tj.src[i] = s_[i]; tj.dst[i] = d_[i];
      tj.src_k[i] = sk_[i]; tj.src_n[i] = sn_[i];
      tj.dst_n[i] = dn_[i]; tj.dst_k[i] = dk_[i];
    }
  }
  transpose_small<<<dim3(2048, 8), 256, 0, stream>>>(tj);

  // 4: LoRA stage-1 (one launch, 320 blocks)
  {
    J128v jv;
    jv.j[0] = { xw, w1T, hw, nullptr, 128, 2048, 2048, 2, 0 };
    jv.j[1] = { xa, a1T, ha, nullptr, 128, 2048, 2048, 1, 64 };
    jv.j[2] = { xv, v1T, hv, nullptr, 128, 2048, 2048, 1, 128 };
    jv.j[3] = { xg, g1T, hg, nullptr, 256, 2048, 2048, 3, 192 };
    gemm128<<<320, 256, 0, stream>>>(jv);
  }
  // 5: r,k,v projections (one 768-block 256^2 pipelined launch)
  {
    G256 g;
    g.A[0] = xr; g.B[0] = Wr16; g.C[0] = r16;
    g.A[1] = xk; g.B[1] = Wk16; g.C[1] = k16;
    g.A[2] = xv; g.B[2] = Wv16; g.C[2] = v0buf;
    gemm256<1><<<768, 512, 0, stream>>>(g);
  }
  // 6: LoRA stage-2 (one launch, 4096 blocks; w-job overwrites weight casts -> after 5)
  {
    J128v jv;
    jv.j[0] = { hw, w2T, w_sec, w0, 2048, 128, 128, 4, 0 };
    jv.j[1] = { ha, a2T, a_sec, a0, 2048, 128, 128, 5, 1024 };
    jv.j[2] = { hv, v2T, vsbuf, v0, 2048, 128, 128, 6, 2048 };
    jv.j[3] = { hg, g2T, gbuf, nullptr, 2048, 256, 256, 1, 3072 };
    gemm128<<<4096, 256, 0, stream>>>(jv);
  }
  // 7: fused per-head epilogue -> kk + z
  ew_head<<<65536, 256, 0, stream>>>(r16, k16, kk_sec, a_sec, v0buf, vsbuf, gbuf,
                                     y, vf, k_k, k_a, r_k, lng, lnb, zbuf);
  // 8: final projection (overwrites out_sec; r16/k16 dead)
  {
    G256 g;
    g.A[0] = zbuf; g.B[0] = Wo16; g.C[0] = out_sec;
    g.A[1] = zbuf; g.B[1] = Wo16; g.C[1] = out_sec;
    g.A[2] = zbuf; g.B[2] = Wo16; g.C[2] = out_sec;
    gemm256<0><<<256, 512, 0, stream>>>(g);
  }
}

// Round 4
// 801.941 us; speedup vs baseline: 1.2872x; 1.2872x over previous
//
#include <hip/hip_runtime.h>
#include <math.h>

typedef unsigned short u16;
typedef __attribute__((ext_vector_type(8))) short short8;
typedef __attribute__((ext_vector_type(4))) float floatx4;
typedef __attribute__((ext_vector_type(4))) unsigned short ushort4v;

#define DEV static __device__ __forceinline__

DEV u16 f2b(float f) {
  unsigned u = __builtin_bit_cast(unsigned, f);
  u += 0x7fffu + ((u >> 16) & 1u);
  return (u16)(u >> 16);
}
DEV float b2f(u16 h) { return __builtin_bit_cast(float, ((unsigned)h) << 16); }

DEV void gld16(const u16* g, u16* l) {
  __builtin_amdgcn_global_load_lds((__attribute__((address_space(1))) void*)(g),
                                   (__attribute__((address_space(3))) void*)(l), 16, 0, 0);
}

// ---------------- K1: token-shift mixes -> 6 bf16 tensors ----------------
__global__ __launch_bounds__(256) void ew_mix(
    const float* __restrict__ x,
    const float* __restrict__ cr, const float* __restrict__ ck,
    const float* __restrict__ cv, const float* __restrict__ cw,
    const float* __restrict__ ca, const float* __restrict__ cg,
    u16* __restrict__ oxr, u16* __restrict__ oxk, u16* __restrict__ oxv,
    u16* __restrict__ oxw, u16* __restrict__ oxa, u16* __restrict__ oxg)
{
  const long idx = (long)blockIdx.x * 256 + threadIdx.x;
  const long row = idx >> 9;
  const int c4 = (int)(idx & 511) << 2;
  const long off = (row << 11) + c4;
  const float4 xc = *(const float4*)(x + off);
  float4 xp = make_float4(0.f, 0.f, 0.f, 0.f);
  if ((row & 4095) != 0) xp = *(const float4*)(x + off - 2048);
  const float xx0 = xp.x - xc.x, xx1 = xp.y - xc.y, xx2 = xp.z - xc.z, xx3 = xp.w - xc.w;
#define EMIT(cp, op) { const float4 cf = *(const float4*)(cp + c4);            \
    ushort4v o = { f2b(xc.x + xx0*cf.x), f2b(xc.y + xx1*cf.y),                 \
                   f2b(xc.z + xx2*cf.z), f2b(xc.w + xx3*cf.w) };               \
    *(ushort4v*)(op + off) = o; }
  EMIT(cr, oxr); EMIT(ck, oxk); EMIT(cv, oxv);
  EMIT(cw, oxw); EMIT(ca, oxa); EMIT(cg, oxg);
#undef EMIT
}

// ---------------- K2: cast 4 big square weights f32 -> bf16 ----------------
__global__ __launch_bounds__(256) void cast_w4(
    const float* __restrict__ s0, const float* __restrict__ s1,
    const float* __restrict__ s2, const float* __restrict__ s3,
    u16* __restrict__ d0, u16* __restrict__ d1, u16* __restrict__ d2, u16* __restrict__ d3)
{
  const float* s; u16* d;
  switch (blockIdx.y) {
    case 0: s = s0; d = d0; break;
    case 1: s = s1; d = d1; break;
    case 2: s = s2; d = d2; break;
    default: s = s3; d = d3; break;
  }
  const long i = ((long)blockIdx.x * 256 + threadIdx.x) * 8;
  const float4 a = *(const float4*)(s + i);
  const float4 b = *(const float4*)(s + i + 4);
  ushort4v lo = { f2b(a.x), f2b(a.y), f2b(a.z), f2b(a.w) };
  ushort4v hi = { f2b(b.x), f2b(b.y), f2b(b.z), f2b(b.w) };
  *(ushort4v*)(d + i) = lo;
  *(ushort4v*)(d + i + 4) = hi;
}

// ---------------- K3: transpose (+zero-pad) LoRA weights -> bf16 [N][K] ----------------
// Flat args; per-job dims are compile-time literals inside the switch.
__global__ __launch_bounds__(256) void transpose_small(
    const float* __restrict__ w1, const float* __restrict__ a1,
    const float* __restrict__ v1, const float* __restrict__ g1,
    const float* __restrict__ w2, const float* __restrict__ a2,
    const float* __restrict__ v2, const float* __restrict__ g2,
    u16* __restrict__ w1T, u16* __restrict__ a1T, u16* __restrict__ v1T,
    u16* __restrict__ g1T, u16* __restrict__ w2T, u16* __restrict__ a2T,
    u16* __restrict__ v2T, u16* __restrict__ g2T)
{
  const long idx = (long)blockIdx.x * 256 + threadIdx.x;
  const float* src; u16* dst; int sk, sn, dn, dk;
  switch (blockIdx.y) {
    case 0: src = w1; dst = w1T; sk = 2048; sn = 128; dn = 128;  dk = 2048; break;
    case 1: src = a1; dst = a1T; sk = 2048; sn = 128; dn = 128;  dk = 2048; break;
    case 2: src = v1; dst = v1T; sk = 2048; sn = 64;  dn = 128;  dk = 2048; break;
    case 3: src = g1; dst = g1T; sk = 2048; sn = 224; dn = 256;  dk = 2048; break;
    case 4: src = w2; dst = w2T; sk = 128;  sn = 2048; dn = 2048; dk = 128; break;
    case 5: src = a2; dst = a2T; sk = 128;  sn = 2048; dn = 2048; dk = 128; break;
    case 6: src = v2; dst = v2T; sk = 64;   sn = 2048; dn = 2048; dk = 128; break;
    default:src = g2; dst = g2T; sk = 224;  sn = 2048; dn = 2048; dk = 256; break;
  }
  const long total = (long)dn * dk;
  if (idx >= total) return;
  const int n = (int)(idx / dk), k = (int)(idx % dk);
  float v = 0.f;
  if (k < sk && n < sn) v = src[(long)k * sn + n];
  dst[idx] = f2b(v);
}

// ---------------- GEMM 128x128 (m97 structure), flat args, template op ----------------
// OP: 1=bf16  2=tanh->bf16  3=sig->bf16  4=w-f32(+bias)  5=sig-f32(+bias)  6=sig-bf16(+bias)
template<int OP>
__global__ __launch_bounds__(256, 2) void gemm_bt(
    const u16* __restrict__ A, const u16* __restrict__ B,
    void* __restrict__ Cv, const float* __restrict__ bias, int N, int K)
{
  __shared__ __align__(16) u16 sA[128 * 64];
  __shared__ __align__(16) u16 sB[128 * 64];
  const int tid = threadIdx.x;
  const int wave = tid >> 6, lane = tid & 63;
  const int lrow = lane & 15, lkg = lane >> 4;
  const int wm = wave >> 1, wn = wave & 1;
  const int nbn = N >> 7;
  const int bm = blockIdx.x / nbn, bn = blockIdx.x % nbn;

  const u16* Abase = A + (long)bm * 128 * K;
  const u16* Bbase = B + (long)bn * 128 * K;

  floatx4 acc[4][4];
#pragma unroll
  for (int i = 0; i < 4; ++i)
#pragma unroll
    for (int j = 0; j < 4; ++j) acc[i][j] = (floatx4)0.f;

  const int nK = K >> 6;
  for (int kt = 0; kt < nK; ++kt) {
    const int k0 = kt << 6;
    __syncthreads();
#pragma unroll
    for (int i = 0; i < 4; ++i) {
      const int c = i * 256 + tid;
      const int row = c >> 3;
      const int sch = (c & 7) ^ (row & 7);
      const long goff = (long)row * K + k0 + sch * 8;
      const int lbase = (i * 256 + wave * 64) * 8;
      gld16(Abase + goff, &sA[lbase]);
      gld16(Bbase + goff, &sB[lbase]);
    }
    asm volatile("s_waitcnt vmcnt(0)" ::: "memory");
    __syncthreads();
#pragma unroll
    for (int ks = 0; ks < 2; ++ks) {
      short8 af[4], bfr[4];
#pragma unroll
      for (int mi = 0; mi < 4; ++mi) {
        const int row = wm * 64 + mi * 16 + lrow;
        const int ch = (ks * 4 + lkg) ^ (row & 7);
        af[mi] = *(const short8*)&sA[row * 64 + ch * 8];
      }
#pragma unroll
      for (int ni = 0; ni < 4; ++ni) {
        const int row = wn * 64 + ni * 16 + lrow;
        const int ch = (ks * 4 + lkg) ^ (row & 7);
        bfr[ni] = *(const short8*)&sB[row * 64 + ch * 8];
      }
#pragma unroll
      for (int mi = 0; mi < 4; ++mi)
#pragma unroll
        for (int ni = 0; ni < 4; ++ni)
          acc[mi][ni] = __builtin_amdgcn_mfma_f32_16x16x32_bf16(af[mi], bfr[ni], acc[mi][ni], 0, 0, 0);
    }
  }

  const int row0 = bm * 128 + wm * 64 + lkg * 4;
  const int col0 = bn * 128 + wn * 64 + lrow;
#pragma unroll
  for (int mi = 0; mi < 4; ++mi) {
#pragma unroll
    for (int ni = 0; ni < 4; ++ni) {
      const int col = col0 + ni * 16;
#pragma unroll
      for (int r = 0; r < 4; ++r) {
        const long o = (long)(row0 + mi * 16 + r) * N + col;
        const float v = acc[mi][ni][r];
        if constexpr (OP == 1) ((u16*)Cv)[o] = f2b(v);
        else if constexpr (OP == 2) ((u16*)Cv)[o] = f2b(tanhf(v));
        else if constexpr (OP == 3) ((u16*)Cv)[o] = f2b(1.f / (1.f + expf(-v)));
        else if constexpr (OP == 4) {
          const float zz = -(v + bias[col]);
          const float sp = fmaxf(zz, 0.f) + log1pf(expf(-fabsf(zz)));
          ((float*)Cv)[o] = -sp - 0.5f;
        } else if constexpr (OP == 5) {
          ((float*)Cv)[o] = 1.f / (1.f + expf(-(v + bias[col])));
        } else {  // 6
          ((u16*)Cv)[o] = f2b(1.f / (1.f + expf(-(v + bias[col]))));
        }
      }
    }
  }
}

// ---------------- GEMM 256x256 deep-pipelined (8-phase, counted vmcnt) ----------------
// Fixed M=8192, N=2048, K=2048 per job. C = A @ B^T, bf16 in. Flat args only.
template<int OP>  // 0=f32 out, 1=bf16 out
__global__ __launch_bounds__(512, 2) void gemm256(
    const u16* __restrict__ A0, const u16* __restrict__ B0, void* __restrict__ C0,
    const u16* __restrict__ A1, const u16* __restrict__ B1, void* __restrict__ C1,
    const u16* __restrict__ A2, const u16* __restrict__ B2, void* __restrict__ C2)
{
  __shared__ __align__(16) u16 lds[8 * 8192];
  const int tid = threadIdx.x;
  const int wave = tid >> 6, lane = tid & 63;
  const int lrow = lane & 15, lq = lane >> 4;
  const int wm = wave >> 2, wn = wave & 3;
  const int job = blockIdx.x >> 8;
  const int lb = blockIdx.x & 255;
  const int bm = lb >> 3, bn = lb & 7;

  // scalar ternary select (s_cselect) — no struct, no alloca
  const u16* Aj = (job == 0) ? A0 : ((job == 1) ? A1 : A2);
  const u16* Bj = (job == 0) ? B0 : ((job == 1) ? B1 : B2);
  void* Cj      = (job == 0) ? C0 : ((job == 1) ? C1 : C2);

  const u16* __restrict__ Ab = Aj + (long)bm * 256 * 2048;
  const u16* __restrict__ Bb = Bj + (long)bn * 256 * 2048;

  int srco[2], dsto[2];
#pragma unroll
  for (int l = 0; l < 2; ++l) {
    const int c = l * 512 + tid;
    const int row = c >> 2, q = c & 3;
    const int qs = q ^ ((row >> 1) & 3);
    srco[l] = row * 2048 + qs * 8;
    dsto[l] = (l * 512 + wave * 64) * 8;
  }
  int offA[2][4], offB[4];
#pragma unroll
  for (int qm = 0; qm < 2; ++qm)
#pragma unroll
    for (int mi = 0; mi < 4; ++mi) {
      const int r = wm * 128 + qm * 64 + mi * 16 + lrow;
      offA[qm][mi] = r * 32 + (lq ^ ((r >> 1) & 3)) * 8;
    }
#pragma unroll
  for (int ni = 0; ni < 4; ++ni) {
    const int r = wn * 64 + ni * 16 + lrow;
    offB[ni] = r * 32 + (lq ^ ((r >> 1) & 3)) * 8;
  }

  floatx4 acc[8][4];
#pragma unroll
  for (int i = 0; i < 8; ++i)
#pragma unroll
    for (int jq = 0; jq < 4; ++jq) acc[i][jq] = (floatx4)0.f;

#define STAGE(sU, slot) {                                                  \
    const int t_ = (sU) >> 2, j_ = (sU) & 3;                               \
    const u16* base_ = (j_ & 1) ? Bb : Ab;                                 \
    const int kofs_ = t_ * 64 + ((j_ & 2) ? 32 : 0);                       \
    gld16(base_ + srco[0] + kofs_, &lds[(slot) * 8192 + dsto[0]]);         \
    gld16(base_ + srco[1] + kofs_, &lds[(slot) * 8192 + dsto[1]]);         \
  }

#pragma unroll
  for (int s = 0; s < 6; ++s) STAGE(s, s);
  asm volatile("s_waitcnt vmcnt(4)" ::: "memory");
  asm volatile("s_barrier" ::: "memory");

  const int nT = 32;
  for (int te = 0; te < nT; te += 2) {
#pragma unroll
    for (int ph = 0; ph < 8; ++ph) {
      const int ks = (ph >> 1) & 1, qm = ph & 1;
      const int slotA = (ph & 4) ? (4 + 2 * ks) : (2 * ks);
      const int slotB = slotA + 1;
      short8 af[4], bf[4];
#pragma unroll
      for (int mi = 0; mi < 4; ++mi)
        af[mi] = *(const short8*)&lds[slotA * 8192 + offA[qm][mi]];
#pragma unroll
      for (int ni = 0; ni < 4; ++ni)
        bf[ni] = *(const short8*)&lds[slotB * 8192 + offB[ni]];
      const int sU = 4 * te + 6 + ph;
      if (sU < 4 * nT) { STAGE(sU, (6 + ph) & 7); }
      if ((ph & 3) == 3) asm volatile("s_waitcnt vmcnt(4)" ::: "memory");
      asm volatile("s_barrier" ::: "memory");
      __builtin_amdgcn_s_setprio(1);
      const int am = qm * 4;
#pragma unroll
      for (int mi = 0; mi < 4; ++mi)
#pragma unroll
        for (int ni = 0; ni < 4; ++ni)
          acc[am + mi][ni] = __builtin_amdgcn_mfma_f32_16x16x32_bf16(af[mi], bf[ni], acc[am + mi][ni], 0, 0, 0);
      __builtin_amdgcn_s_setprio(0);
      asm volatile("s_barrier" ::: "memory");
    }
  }
#undef STAGE

  const long row0 = (long)bm * 256 + wm * 128 + lq * 4;
  const int col0 = bn * 256 + wn * 64 + lrow;
#pragma unroll
  for (int mi = 0; mi < 8; ++mi) {
#pragma unroll
    for (int ni = 0; ni < 4; ++ni) {
      const int col = col0 + ni * 16;
#pragma unroll
      for (int r = 0; r < 4; ++r) {
        const long o = (row0 + mi * 16 + r) * 2048 + col;
        const float v = acc[mi][ni][r];
        if constexpr (OP == 0) ((float*)Cj)[o] = v;
        else ((u16*)Cj)[o] = f2b(v);
      }
    }
  }
}

// ---------------- K6: per-head fused epilogue ----------------
DEV float wsum64(float v) {
  v += __shfl_xor(v, 1);  v += __shfl_xor(v, 2);  v += __shfl_xor(v, 4);
  v += __shfl_xor(v, 8);  v += __shfl_xor(v, 16); v += __shfl_xor(v, 32);
  return v;
}

__global__ __launch_bounds__(256) void ew_head(
    const u16* __restrict__ r16, const u16* __restrict__ k16,
    float* __restrict__ kkout,
    const float* __restrict__ abuf,
    const u16* __restrict__ v0buf, const u16* __restrict__ vsbuf,
    const u16* __restrict__ gbuf,
    const float* __restrict__ y, const float* __restrict__ vfirst,
    const float* __restrict__ kkc, const float* __restrict__ kac,
    const float* __restrict__ rk, const float* __restrict__ lng,
    const float* __restrict__ lnb, u16* __restrict__ z)
{
  const int tid = threadIdx.x;
  const int wave = tid >> 6, lane = tid & 63;
  const long gh = (long)blockIdx.x * 4 + wave;
  const long m = gh >> 5;
  const int h = (int)(gh & 31);
  const int c = h * 64 + lane;
  const long off = (m << 11) + c;

  const float k0 = b2f(k16[off]);
  const float av = abuf[off];
  const float kf = k0 * (1.f + (av - 1.f) * kac[c]);
  const float kkr = k0 * kkc[c];
  const float nrm = sqrtf(wsum64(kkr * kkr));
  kkout[off] = kkr / fmaxf(nrm, 1e-12f);

  const float yv = y[off];
  const float mu = wsum64(yv) * 0.015625f;
  const float dy = yv - mu;
  const float var = wsum64(dy * dy) * 0.015625f;
  const float yn = dy * rsqrtf(var + 0.00064f) * lng[c] + lnb[c];

  const float dot = wsum64(b2f(r16[off]) * kf * rk[c]);

  const float v0v = b2f(v0buf[off]);
  const float sv = b2f(vsbuf[off]);
  const float vv = v0v + (vfirst[off] - v0v) * sv;

  const float y2 = yn + dot * vv;
  z[off] = f2b(y2 * b2f(gbuf[off]));
}

// ---------------- launch ----------------
extern "C" void kernel_launch(void* const* d_in, const int* in_sizes, int n_in,
                              void* d_out, int out_size, void* d_ws, size_t ws_size,
                              hipStream_t stream)
{
  (void)in_sizes; (void)out_size;
  if (n_in < 29) return;
  const int Mrows = 8192;
  const long C = 2048;
  const long MB_ = (long)Mrows * C;

  const float* x   = (const float*)d_in[0];
  const float* vf  = (const float*)d_in[1];
  const float* y   = (const float*)d_in[2];
  const float* x_r = (const float*)d_in[3];
  const float* x_w = (const float*)d_in[4];
  const float* x_k = (const float*)d_in[5];
  const float* x_v = (const float*)d_in[6];
  const float* x_a = (const float*)d_in[7];
  const float* x_g = (const float*)d_in[8];
  const float* w0  = (const float*)d_in[9];
  const float* w1  = (const float*)d_in[10];
  const float* w2  = (const float*)d_in[11];
  const float* a0  = (const float*)d_in[12];
  const float* a1  = (const float*)d_in[13];
  const float* a2  = (const float*)d_in[14];
  const float* v0  = (const float*)d_in[15];
  const float* v1  = (const float*)d_in[16];
  const float* v2  = (const float*)d_in[17];
  const float* g1  = (const float*)d_in[18];
  const float* g2  = (const float*)d_in[19];
  const float* k_k = (const float*)d_in[20];
  const float* k_a = (const float*)d_in[21];
  const float* r_k = (const float*)d_in[22];
  const float* W_r = (const float*)d_in[23];
  const float* W_k = (const float*)d_in[24];
  const float* W_v = (const float*)d_in[25];
  const float* W_o = (const float*)d_in[26];
  const float* lng = (const float*)d_in[27];
  const float* lnb = (const float*)d_in[28];

  float* out_sec = (float*)d_out;
  float* w_sec   = out_sec + MB_;
  float* a_sec   = w_sec + MB_;
  float* kk_sec  = a_sec + MB_;

  u16* k16 = (u16*)out_sec;            // dead d_out regions until final GEMM
  u16* r16 = (u16*)out_sec + MB_;
  u16* Wr16 = (u16*)w_sec;             // weight casts; dead before stage-2 writes w_sec
  u16* Wk16 = Wr16 + C * C;
  u16* Wv16 = Wk16 + C * C;

  u16* p = (u16*)d_ws;
  u16* xr = p;            p += MB_;
  u16* xk = p;            p += MB_;   // later z
  u16* xv = p;            p += MB_;
  u16* xw = p;            p += MB_;   // later vs
  u16* xa = p;            p += MB_;   // later g
  u16* xg = p;            p += MB_;   // later v0
  u16* Wo16 = p;          p += C * C;
  u16* w1T = p;           p += 128 * C;
  u16* a1T = p;           p += 128 * C;
  u16* v1T = p;           p += 128 * C;
  u16* g1T = p;           p += 256 * C;
  u16* w2T = p;           p += C * 128;
  u16* a2T = p;           p += C * 128;
  u16* v2T = p;           p += C * 128;
  u16* g2T = p;           p += C * 256;
  u16* hw  = p;           p += (long)Mrows * 128;
  u16* ha  = p;           p += (long)Mrows * 128;
  u16* hv  = p;           p += (long)Mrows * 128;
  u16* hg  = p;           p += (long)Mrows * 256;
  const size_t need = (size_t)((char*)p - (char*)d_ws);
  if (ws_size < need) return;

  u16* v0buf = xg;   // xg dead after stage-1; written by gemm256 job 2
  u16* zbuf  = xk;   // xk dead after gemm256 reads it
  u16* vsbuf = xw;   // xw dead after stage-1
  u16* gbuf  = xa;   // xa dead after stage-1

  // 1: mixes
  ew_mix<<<16384, 256, 0, stream>>>(x, x_r, x_k, x_v, x_w, x_a, x_g,
                                    xr, xk, xv, xw, xa, xg);
  // 2: big weight casts
  cast_w4<<<dim3(2048, 4), 256, 0, stream>>>(W_r, W_k, W_v, W_o, Wr16, Wk16, Wv16, Wo16);
  // 3: LoRA weight transposes (+zero pad)
  transpose_small<<<dim3(2048, 8), 256, 0, stream>>>(
      w1, a1, v1, g1, w2, a2, v2, g2,
      w1T, a1T, v1T, g1T, w2T, a2T, v2T, g2T);
  // 4: LoRA stage-1 (flat-arg, separate launches)
  gemm_bt<2><<<64,  256, 0, stream>>>(xw, w1T, hw, nullptr, 128, 2048);
  gemm_bt<1><<<64,  256, 0, stream>>>(xa, a1T, ha, nullptr, 128, 2048);
  gemm_bt<1><<<64,  256, 0, stream>>>(xv, v1T, hv, nullptr, 128, 2048);
  gemm_bt<3><<<128, 256, 0, stream>>>(xg, g1T, hg, nullptr, 256, 2048);
  // 5: r,k,v projections (one 768-block 256^2 pipelined launch)
  gemm256<1><<<768, 512, 0, stream>>>(xr, Wr16, r16,
                                      xk, Wk16, k16,
                                      xv, Wv16, v0buf);
  // 6: LoRA stage-2 (w-job overwrites weight casts -> after 5)
  gemm_bt<4><<<1024, 256, 0, stream>>>(hw, w2T, w_sec, w0, 2048, 128);
  gemm_bt<5><<<1024, 256, 0, stream>>>(ha, a2T, a_sec, a0, 2048, 128);
  gemm_bt<6><<<1024, 256, 0, stream>>>(hv, v2T, vsbuf, v0, 2048, 128);
  gemm_bt<1><<<1024, 256, 0, stream>>>(hg, g2T, gbuf, nullptr, 2048, 256);
  // 7: fused per-head epilogue -> kk + z
  ew_head<<<65536, 256, 0, stream>>>(r16, k16, kk_sec, a_sec, v0buf, vsbuf, gbuf,
                                     y, vf, k_k, k_a, r_k, lng, lnb, zbuf);
  // 8: final projection (overwrites out_sec; r16/k16 dead)
  gemm256<0><<<256, 512, 0, stream>>>(zbuf, Wo16, out_sec,
                                      zbuf, Wo16, out_sec,
                                      zbuf, Wo16, out_sec);
}

// Round 5
// 707.769 us; speedup vs baseline: 1.4585x; 1.1331x over previous
//
#include <hip/hip_runtime.h>
#include <math.h>

typedef unsigned short u16;
typedef __attribute__((ext_vector_type(8))) short short8;
typedef __attribute__((ext_vector_type(4))) float floatx4;
typedef __attribute__((ext_vector_type(4))) unsigned short ushort4v;

#define DEV static __device__ __forceinline__

DEV u16 f2b(float f) {
  unsigned u = __builtin_bit_cast(unsigned, f);
  u += 0x7fffu + ((u >> 16) & 1u);
  return (u16)(u >> 16);
}
DEV float b2f(u16 h) { return __builtin_bit_cast(float, ((unsigned)h) << 16); }

DEV void gld16(const u16* g, u16* l) {
  __builtin_amdgcn_global_load_lds((__attribute__((address_space(1))) void*)(g),
                                   (__attribute__((address_space(3))) void*)(l), 16, 0, 0);
}

// ---------------- K1: token-shift mixes -> 6 bf16 tensors ----------------
__global__ __launch_bounds__(256) void ew_mix(
    const float* __restrict__ x,
    const float* __restrict__ cr, const float* __restrict__ ck,
    const float* __restrict__ cv, const float* __restrict__ cw,
    const float* __restrict__ ca, const float* __restrict__ cg,
    u16* __restrict__ oxr, u16* __restrict__ oxk, u16* __restrict__ oxv,
    u16* __restrict__ oxw, u16* __restrict__ oxa, u16* __restrict__ oxg)
{
  const long idx = (long)blockIdx.x * 256 + threadIdx.x;
  const long row = idx >> 9;
  const int c4 = (int)(idx & 511) << 2;
  const long off = (row << 11) + c4;
  const float4 xc = *(const float4*)(x + off);
  float4 xp = make_float4(0.f, 0.f, 0.f, 0.f);
  if ((row & 4095) != 0) xp = *(const float4*)(x + off - 2048);
  const float xx0 = xp.x - xc.x, xx1 = xp.y - xc.y, xx2 = xp.z - xc.z, xx3 = xp.w - xc.w;
#define EMIT(cp, op) { const float4 cf = *(const float4*)(cp + c4);            \
    ushort4v o = { f2b(xc.x + xx0*cf.x), f2b(xc.y + xx1*cf.y),                 \
                   f2b(xc.z + xx2*cf.z), f2b(xc.w + xx3*cf.w) };               \
    *(ushort4v*)(op + off) = o; }
  EMIT(cr, oxr); EMIT(ck, oxk); EMIT(cv, oxv);
  EMIT(cw, oxw); EMIT(ca, oxa); EMIT(cg, oxg);
#undef EMIT
}

// ---------------- K2: cast 4 big square weights f32 -> bf16 ----------------
__global__ __launch_bounds__(256) void cast_w4(
    const float* __restrict__ s0, const float* __restrict__ s1,
    const float* __restrict__ s2, const float* __restrict__ s3,
    u16* __restrict__ d0, u16* __restrict__ d1, u16* __restrict__ d2, u16* __restrict__ d3)
{
  const float* s; u16* d;
  switch (blockIdx.y) {
    case 0: s = s0; d = d0; break;
    case 1: s = s1; d = d1; break;
    case 2: s = s2; d = d2; break;
    default: s = s3; d = d3; break;
  }
  const long i = ((long)blockIdx.x * 256 + threadIdx.x) * 8;
  const float4 a = *(const float4*)(s + i);
  const float4 b = *(const float4*)(s + i + 4);
  ushort4v lo = { f2b(a.x), f2b(a.y), f2b(a.z), f2b(a.w) };
  ushort4v hi = { f2b(b.x), f2b(b.y), f2b(b.z), f2b(b.w) };
  *(ushort4v*)(d + i) = lo;
  *(ushort4v*)(d + i + 4) = hi;
}

// ---------------- K3: transpose (+zero-pad) LoRA weights -> bf16 [N][K] ----------------
__global__ __launch_bounds__(256) void transpose_small(
    const float* __restrict__ w1, const float* __restrict__ a1,
    const float* __restrict__ v1, const float* __restrict__ g1,
    const float* __restrict__ w2, const float* __restrict__ a2,
    const float* __restrict__ v2, const float* __restrict__ g2,
    u16* __restrict__ w1T, u16* __restrict__ a1T, u16* __restrict__ v1T,
    u16* __restrict__ g1T, u16* __restrict__ w2T, u16* __restrict__ a2T,
    u16* __restrict__ v2T, u16* __restrict__ g2T)
{
  const long idx = (long)blockIdx.x * 256 + threadIdx.x;
  const float* src; u16* dst; int sk, sn, dn, dk;
  switch (blockIdx.y) {
    case 0: src = w1; dst = w1T; sk = 2048; sn = 128; dn = 128;  dk = 2048; break;
    case 1: src = a1; dst = a1T; sk = 2048; sn = 128; dn = 128;  dk = 2048; break;
    case 2: src = v1; dst = v1T; sk = 2048; sn = 64;  dn = 128;  dk = 2048; break;
    case 3: src = g1; dst = g1T; sk = 2048; sn = 224; dn = 256;  dk = 2048; break;
    case 4: src = w2; dst = w2T; sk = 128;  sn = 2048; dn = 2048; dk = 128; break;
    case 5: src = a2; dst = a2T; sk = 128;  sn = 2048; dn = 2048; dk = 128; break;
    case 6: src = v2; dst = v2T; sk = 64;   sn = 2048; dn = 2048; dk = 128; break;
    default:src = g2; dst = g2T; sk = 224;  sn = 2048; dn = 2048; dk = 256; break;
  }
  const long total = (long)dn * dk;
  if (idx >= total) return;
  const int n = (int)(idx / dk), k = (int)(idx % dk);
  float v = 0.f;
  if (k < sk && n < sn) v = src[(long)k * sn + n];
  dst[idx] = f2b(v);
}

// ---------------- shared 128x128 GEMM body (m97 structure) ----------------
// Computes acc for C-tile (bm,bn). Caller handles epilogue.
#define GEMM128_BODY(Abase, Bbase, K)                                          \
  floatx4 acc[4][4];                                                           \
  _Pragma("unroll")                                                            \
  for (int i = 0; i < 4; ++i)                                                  \
    _Pragma("unroll")                                                          \
    for (int jq = 0; jq < 4; ++jq) acc[i][jq] = (floatx4)0.f;                  \
  const int nK = (K) >> 6;                                                     \
  for (int kt = 0; kt < nK; ++kt) {                                            \
    const int k0 = kt << 6;                                                    \
    __syncthreads();                                                           \
    _Pragma("unroll")                                                          \
    for (int i = 0; i < 4; ++i) {                                              \
      const int c = i * 256 + tid;                                             \
      const int row = c >> 3;                                                  \
      const int sch = (c & 7) ^ (row & 7);                                     \
      const long goff = (long)row * (K) + k0 + sch * 8;                        \
      const int lbase = (i * 256 + wave * 64) * 8;                             \
      gld16((Abase) + goff, &sA[lbase]);                                       \
      gld16((Bbase) + goff, &sB[lbase]);                                       \
    }                                                                          \
    asm volatile("s_waitcnt vmcnt(0)" ::: "memory");                           \
    __syncthreads();                                                           \
    _Pragma("unroll")                                                          \
    for (int ks = 0; ks < 2; ++ks) {                                           \
      short8 af[4], bfr[4];                                                    \
      _Pragma("unroll")                                                        \
      for (int mi = 0; mi < 4; ++mi) {                                         \
        const int row = wm * 64 + mi * 16 + lrow;                              \
        const int ch = (ks * 4 + lkg) ^ (row & 7);                             \
        af[mi] = *(const short8*)&sA[row * 64 + ch * 8];                       \
      }                                                                        \
      _Pragma("unroll")                                                        \
      for (int ni = 0; ni < 4; ++ni) {                                         \
        const int row = wn * 64 + ni * 16 + lrow;                              \
        const int ch = (ks * 4 + lkg) ^ (row & 7);                             \
        bfr[ni] = *(const short8*)&sB[row * 64 + ch * 8];                      \
      }                                                                        \
      _Pragma("unroll")                                                        \
      for (int mi = 0; mi < 4; ++mi)                                           \
        _Pragma("unroll")                                                      \
        for (int ni = 0; ni < 4; ++ni)                                         \
          acc[mi][ni] = __builtin_amdgcn_mfma_f32_16x16x32_bf16(af[mi], bfr[ni], acc[mi][ni], 0, 0, 0); \
    }                                                                          \
  }

// ---------------- merged LoRA stage-1: 4 jobs, one launch ----------------
// blocks: [0,64) w-tanh  [64,128) a  [128,192) v  [192,320) g-sigmoid(N=256)
__global__ __launch_bounds__(256, 2) void gemm_s1(
    const u16* __restrict__ xw, const u16* __restrict__ w1T, u16* __restrict__ hw,
    const u16* __restrict__ xa, const u16* __restrict__ a1T, u16* __restrict__ ha,
    const u16* __restrict__ xv, const u16* __restrict__ v1T, u16* __restrict__ hv,
    const u16* __restrict__ xg, const u16* __restrict__ g1T, u16* __restrict__ hg)
{
  __shared__ __align__(16) u16 sA[128 * 64];
  __shared__ __align__(16) u16 sB[128 * 64];
  const int bid = blockIdx.x;
  const int jid = (bid < 64) ? 0 : (bid < 128) ? 1 : (bid < 192) ? 2 : 3;
  const u16* A = (jid == 0) ? xw : (jid == 1) ? xa : (jid == 2) ? xv : xg;
  const u16* B = (jid == 0) ? w1T : (jid == 1) ? a1T : (jid == 2) ? v1T : g1T;
  u16* Cv = (jid == 0) ? hw : (jid == 1) ? ha : (jid == 2) ? hv : hg;
  const int N = (jid == 3) ? 256 : 128;
  const int lb = bid - ((jid == 0) ? 0 : (jid == 1) ? 64 : (jid == 2) ? 128 : 192);
  const int tid = threadIdx.x;
  const int wave = tid >> 6, lane = tid & 63;
  const int lrow = lane & 15, lkg = lane >> 4;
  const int wm = wave >> 1, wn = wave & 1;
  const int nbn = N >> 7;
  const int bm = lb / nbn, bn = lb % nbn;
  const u16* Abase = A + (long)bm * 128 * 2048;
  const u16* Bbase = B + (long)bn * 128 * 2048;

  GEMM128_BODY(Abase, Bbase, 2048)

  const int row0 = bm * 128 + wm * 64 + lkg * 4;
  const int col0 = bn * 128 + wn * 64 + lrow;
#pragma unroll
  for (int mi = 0; mi < 4; ++mi)
#pragma unroll
    for (int ni = 0; ni < 4; ++ni) {
      const int col = col0 + ni * 16;
#pragma unroll
      for (int r = 0; r < 4; ++r) {
        const long o = (long)(row0 + mi * 16 + r) * N + col;
        float v = acc[mi][ni][r];
        if (jid == 0) v = tanhf(v);
        else if (jid == 3) v = 1.f / (1.f + expf(-v));
        Cv[o] = f2b(v);
      }
    }
}

// ---------------- merged LoRA stage-2: 4 jobs x 1024 blocks ----------------
// j0: w-transform->f32(w_sec)  j1: sigmoid->f32(a_sec)
// j2: sigmoid->bf16(vs)        j3: plain->bf16(gb), K=256
__global__ __launch_bounds__(256, 2) void gemm_s2(
    const u16* __restrict__ hw, const u16* __restrict__ w2T, float* __restrict__ wsec, const float* __restrict__ w0,
    const u16* __restrict__ ha, const u16* __restrict__ a2T, float* __restrict__ asec, const float* __restrict__ a0,
    const u16* __restrict__ hv, const u16* __restrict__ v2T, u16* __restrict__ vs, const float* __restrict__ v0,
    const u16* __restrict__ hg, const u16* __restrict__ g2T, u16* __restrict__ gb)
{
  __shared__ __align__(16) u16 sA[128 * 64];
  __shared__ __align__(16) u16 sB[128 * 64];
  const int jid = blockIdx.x >> 10;
  const int lb = blockIdx.x & 1023;
  const u16* A = (jid == 0) ? hw : (jid == 1) ? ha : (jid == 2) ? hv : hg;
  const u16* B = (jid == 0) ? w2T : (jid == 1) ? a2T : (jid == 2) ? v2T : g2T;
  const float* bias = (jid == 0) ? w0 : (jid == 1) ? a0 : v0;
  const int K = (jid == 3) ? 256 : 128;
  const int tid = threadIdx.x;
  const int wave = tid >> 6, lane = tid & 63;
  const int lrow = lane & 15, lkg = lane >> 4;
  const int wm = wave >> 1, wn = wave & 1;
  const int bm = lb >> 4, bn = lb & 15;   // N=2048 -> 16 bn
  const u16* Abase = A + (long)bm * 128 * K;
  const u16* Bbase = B + (long)bn * 128 * K;

  GEMM128_BODY(Abase, Bbase, K)

  const int row0 = bm * 128 + wm * 64 + lkg * 4;
  const int col0 = bn * 128 + wn * 64 + lrow;
#pragma unroll
  for (int mi = 0; mi < 4; ++mi)
#pragma unroll
    for (int ni = 0; ni < 4; ++ni) {
      const int col = col0 + ni * 16;
#pragma unroll
      for (int r = 0; r < 4; ++r) {
        const long o = (long)(row0 + mi * 16 + r) * 2048 + col;
        const float v = acc[mi][ni][r];
        if (jid == 0) {
          const float zz = -(v + bias[col]);
          const float sp = fmaxf(zz, 0.f) + log1pf(expf(-fabsf(zz)));
          wsec[o] = -sp - 0.5f;
        } else if (jid == 1) {
          asec[o] = 1.f / (1.f + expf(-(v + bias[col])));
        } else if (jid == 2) {
          vs[o] = f2b(1.f / (1.f + expf(-(v + bias[col]))));
        } else {
          gb[o] = f2b(v);
        }
      }
    }
}

// ---------------- GEMM 256x256 deep-pipelined (8-phase, counted vmcnt) ----------------
// Fixed M=8192, N=2048, K=2048 per job. C = A @ B^T, bf16 in. Flat args only.
// B-fragments held in registers across the two m-half phases: 24 ds_read/tile
// (was 32) -> relieves the CU LDS-read port (this round's lever).
template<int OP>  // 0=f32 out, 1=bf16 out
__global__ __launch_bounds__(512, 2) void gemm256(
    const u16* __restrict__ A0, const u16* __restrict__ B0, void* __restrict__ C0,
    const u16* __restrict__ A1, const u16* __restrict__ B1, void* __restrict__ C1,
    const u16* __restrict__ A2, const u16* __restrict__ B2, void* __restrict__ C2)
{
  __shared__ __align__(16) u16 lds[8 * 8192];
  const int tid = threadIdx.x;
  const int wave = tid >> 6, lane = tid & 63;
  const int lrow = lane & 15, lq = lane >> 4;
  const int wm = wave >> 2, wn = wave & 3;
  const int job = blockIdx.x >> 8;
  const int lb = blockIdx.x & 255;
  const int bm = lb >> 3, bn = lb & 7;

  const u16* Aj = (job == 0) ? A0 : ((job == 1) ? A1 : A2);
  const u16* Bj = (job == 0) ? B0 : ((job == 1) ? B1 : B2);
  void* Cj      = (job == 0) ? C0 : ((job == 1) ? C1 : C2);

  const u16* __restrict__ Ab = Aj + (long)bm * 256 * 2048;
  const u16* __restrict__ Bb = Bj + (long)bn * 256 * 2048;

  int srco[2], dsto[2];
#pragma unroll
  for (int l = 0; l < 2; ++l) {
    const int c = l * 512 + tid;
    const int row = c >> 2, q = c & 3;
    const int qs = q ^ ((row >> 1) & 3);
    srco[l] = row * 2048 + qs * 8;
    dsto[l] = (l * 512 + wave * 64) * 8;
  }
  int offA[2][4], offB[4];
#pragma unroll
  for (int qm = 0; qm < 2; ++qm)
#pragma unroll
    for (int mi = 0; mi < 4; ++mi) {
      const int r = wm * 128 + qm * 64 + mi * 16 + lrow;
      offA[qm][mi] = r * 32 + (lq ^ ((r >> 1) & 3)) * 8;
    }
#pragma unroll
  for (int ni = 0; ni < 4; ++ni) {
    const int r = wn * 64 + ni * 16 + lrow;
    offB[ni] = r * 32 + (lq ^ ((r >> 1) & 3)) * 8;
  }

  floatx4 acc[8][4];
#pragma unroll
  for (int i = 0; i < 8; ++i)
#pragma unroll
    for (int jq = 0; jq < 4; ++jq) acc[i][jq] = (floatx4)0.f;

#define STAGE(sU, slot) {                                                  \
    const int t_ = (sU) >> 2, j_ = (sU) & 3;                               \
    const u16* base_ = (j_ & 1) ? Bb : Ab;                                 \
    const int kofs_ = t_ * 64 + ((j_ & 2) ? 32 : 0);                       \
    gld16(base_ + srco[0] + kofs_, &lds[(slot) * 8192 + dsto[0]]);         \
    gld16(base_ + srco[1] + kofs_, &lds[(slot) * 8192 + dsto[1]]);         \
  }

#pragma unroll
  for (int s = 0; s < 6; ++s) STAGE(s, s);
  asm volatile("s_waitcnt vmcnt(4)" ::: "memory");
  asm volatile("s_barrier" ::: "memory");

  short8 bfr[4];   // persists across the qm pair (read only on qm==0 phases)
  const int nT = 32;
  for (int te = 0; te < nT; te += 2) {
#pragma unroll
    for (int ph = 0; ph < 8; ++ph) {
      const int ks = (ph >> 1) & 1, qm = ph & 1;
      const int slotA = ((ph & 4) ? 4 : 0) + 2 * ks;
      const int slotB = slotA + 1;
      short8 af[4];
      if (qm == 0) {
#pragma unroll
        for (int ni = 0; ni < 4; ++ni)
          bfr[ni] = *(const short8*)&lds[slotB * 8192 + offB[ni]];
      }
#pragma unroll
      for (int mi = 0; mi < 4; ++mi)
        af[mi] = *(const short8*)&lds[slotA * 8192 + offA[qm][mi]];
      const int sU = 4 * te + 6 + ph;
      if (sU < 4 * nT) { STAGE(sU, (6 + ph) & 7); }
      if ((ph & 3) == 3) asm volatile("s_waitcnt vmcnt(4)" ::: "memory");
      asm volatile("s_barrier" ::: "memory");
      __builtin_amdgcn_s_setprio(1);
      const int am = qm * 4;
#pragma unroll
      for (int mi = 0; mi < 4; ++mi)
#pragma unroll
        for (int ni = 0; ni < 4; ++ni)
          acc[am + mi][ni] = __builtin_amdgcn_mfma_f32_16x16x32_bf16(af[mi], bfr[ni], acc[am + mi][ni], 0, 0, 0);
      __builtin_amdgcn_s_setprio(0);
      asm volatile("s_barrier" ::: "memory");
    }
  }
#undef STAGE

  const long row0 = (long)bm * 256 + wm * 128 + lq * 4;
  const int col0 = bn * 256 + wn * 64 + lrow;
#pragma unroll
  for (int mi = 0; mi < 8; ++mi) {
#pragma unroll
    for (int ni = 0; ni < 4; ++ni) {
      const int col = col0 + ni * 16;
#pragma unroll
      for (int r = 0; r < 4; ++r) {
        const long o = (row0 + mi * 16 + r) * 2048 + col;
        const float v = acc[mi][ni][r];
        if constexpr (OP == 0) ((float*)Cj)[o] = v;
        else ((u16*)Cj)[o] = f2b(v);
      }
    }
  }
}

// ---------------- K6: per-head fused epilogue ----------------
DEV float wsum64(float v) {
  v += __shfl_xor(v, 1);  v += __shfl_xor(v, 2);  v += __shfl_xor(v, 4);
  v += __shfl_xor(v, 8);  v += __shfl_xor(v, 16); v += __shfl_xor(v, 32);
  return v;
}

__global__ __launch_bounds__(256) void ew_head(
    const u16* __restrict__ r16, const u16* __restrict__ k16,
    float* __restrict__ kkout,
    const float* __restrict__ abuf,
    const u16* __restrict__ v0buf, const u16* __restrict__ vsbuf,
    const u16* __restrict__ gbuf,
    const float* __restrict__ y, const float* __restrict__ vfirst,
    const float* __restrict__ kkc, const float* __restrict__ kac,
    const float* __restrict__ rk, const float* __restrict__ lng,
    const float* __restrict__ lnb, u16* __restrict__ z)
{
  const int tid = threadIdx.x;
  const int wave = tid >> 6, lane = tid & 63;
  const long gh = (long)blockIdx.x * 4 + wave;
  const long m = gh >> 5;
  const int h = (int)(gh & 31);
  const int c = h * 64 + lane;
  const long off = (m << 11) + c;

  const float k0 = b2f(k16[off]);
  const float av = abuf[off];
  const float kf = k0 * (1.f + (av - 1.f) * kac[c]);
  const float kkr = k0 * kkc[c];
  const float nrm = sqrtf(wsum64(kkr * kkr));
  kkout[off] = kkr / fmaxf(nrm, 1e-12f);

  const float yv = y[off];
  const float mu = wsum64(yv) * 0.015625f;
  const float dy = yv - mu;
  const float var = wsum64(dy * dy) * 0.015625f;
  const float yn = dy * rsqrtf(var + 0.00064f) * lng[c] + lnb[c];

  const float dot = wsum64(b2f(r16[off]) * kf * rk[c]);

  const float v0v = b2f(v0buf[off]);
  const float sv = b2f(vsbuf[off]);
  const float vv = v0v + (vfirst[off] - v0v) * sv;

  const float y2 = yn + dot * vv;
  z[off] = f2b(y2 * b2f(gbuf[off]));
}

// ---------------- launch ----------------
extern "C" void kernel_launch(void* const* d_in, const int* in_sizes, int n_in,
                              void* d_out, int out_size, void* d_ws, size_t ws_size,
                              hipStream_t stream)
{
  (void)in_sizes; (void)out_size;
  if (n_in < 29) return;
  const int Mrows = 8192;
  const long C = 2048;
  const long MB_ = (long)Mrows * C;

  const float* x   = (const float*)d_in[0];
  const float* vf  = (const float*)d_in[1];
  const float* y   = (const float*)d_in[2];
  const float* x_r = (const float*)d_in[3];
  const float* x_w = (const float*)d_in[4];
  const float* x_k = (const float*)d_in[5];
  const float* x_v = (const float*)d_in[6];
  const float* x_a = (const float*)d_in[7];
  const float* x_g = (const float*)d_in[8];
  const float* w0  = (const float*)d_in[9];
  const float* w1  = (const float*)d_in[10];
  const float* w2  = (const float*)d_in[11];
  const float* a0  = (const float*)d_in[12];
  const float* a1  = (const float*)d_in[13];
  const float* a2  = (const float*)d_in[14];
  const float* v0  = (const float*)d_in[15];
  const float* v1  = (const float*)d_in[16];
  const float* v2  = (const float*)d_in[17];
  const float* g1  = (const float*)d_in[18];
  const float* g2  = (const float*)d_in[19];
  const float* k_k = (const float*)d_in[20];
  const float* k_a = (const float*)d_in[21];
  const float* r_k = (const float*)d_in[22];
  const float* W_r = (const float*)d_in[23];
  const float* W_k = (const float*)d_in[24];
  const float* W_v = (const float*)d_in[25];
  const float* W_o = (const float*)d_in[26];
  const float* lng = (const float*)d_in[27];
  const float* lnb = (const float*)d_in[28];

  float* out_sec = (float*)d_out;
  float* w_sec   = out_sec + MB_;
  float* a_sec   = w_sec + MB_;
  float* kk_sec  = a_sec + MB_;

  u16* k16 = (u16*)out_sec;            // dead d_out regions until final GEMM
  u16* r16 = (u16*)out_sec + MB_;
  u16* Wr16 = (u16*)w_sec;             // weight casts; dead before stage-2 writes w_sec
  u16* Wk16 = Wr16 + C * C;
  u16* Wv16 = Wk16 + C * C;

  u16* p = (u16*)d_ws;
  u16* xr = p;            p += MB_;
  u16* xk = p;            p += MB_;   // later z
  u16* xv = p;            p += MB_;
  u16* xw = p;            p += MB_;   // later vs
  u16* xa = p;            p += MB_;   // later g
  u16* xg = p;            p += MB_;   // later v0
  u16* Wo16 = p;          p += C * C;
  u16* w1T = p;           p += 128 * C;
  u16* a1T = p;           p += 128 * C;
  u16* v1T = p;           p += 128 * C;
  u16* g1T = p;           p += 256 * C;
  u16* w2T = p;           p += C * 128;
  u16* a2T = p;           p += C * 128;
  u16* v2T = p;           p += C * 128;
  u16* g2T = p;           p += C * 256;
  u16* hw  = p;           p += (long)Mrows * 128;
  u16* ha  = p;           p += (long)Mrows * 128;
  u16* hv  = p;           p += (long)Mrows * 128;
  u16* hg  = p;           p += (long)Mrows * 256;
  const size_t need = (size_t)((char*)p - (char*)d_ws);
  if (ws_size < need) return;

  u16* v0buf = xg;   // xg dead after gemm_s1; written by gemm256 job 2
  u16* zbuf  = xk;   // xk dead after gemm256 reads it
  u16* vsbuf = xw;   // xw dead after gemm_s1
  u16* gbuf  = xa;   // xa dead after gemm_s1

  // 1: mixes
  ew_mix<<<16384, 256, 0, stream>>>(x, x_r, x_k, x_v, x_w, x_a, x_g,
                                    xr, xk, xv, xw, xa, xg);
  // 2: big weight casts
  cast_w4<<<dim3(2048, 4), 256, 0, stream>>>(W_r, W_k, W_v, W_o, Wr16, Wk16, Wv16, Wo16);
  // 3: LoRA weight transposes (+zero pad)
  transpose_small<<<dim3(2048, 8), 256, 0, stream>>>(
      w1, a1, v1, g1, w2, a2, v2, g2,
      w1T, a1T, v1T, g1T, w2T, a2T, v2T, g2T);
  // 4: LoRA stage-1 (one 320-block launch)
  gemm_s1<<<320, 256, 0, stream>>>(xw, w1T, hw, xa, a1T, ha,
                                   xv, v1T, hv, xg, g1T, hg);
  // 5: r,k,v projections (one 768-block 256^2 pipelined launch)
  gemm256<1><<<768, 512, 0, stream>>>(xr, Wr16, r16,
                                      xk, Wk16, k16,
                                      xv, Wv16, v0buf);
  // 6: LoRA stage-2 (one 4096-block launch; w-job overwrites weight casts -> after 5)
  gemm_s2<<<4096, 256, 0, stream>>>(hw, w2T, w_sec, w0,
                                    ha, a2T, a_sec, a0,
                                    hv, v2T, vsbuf, v0,
                                    hg, g2T, gbuf);
  // 7: fused per-head epilogue -> kk + z
  ew_head<<<65536, 256, 0, stream>>>(r16, k16, kk_sec, a_sec, v0buf, vsbuf, gbuf,
                                     y, vf, k_k, k_a, r_k, lng, lnb, zbuf);
  // 8: final projection (overwrites out_sec; r16/k16 dead)
  gemm256<0><<<256, 512, 0, stream>>>(zbuf, Wo16, out_sec,
                                      zbuf, Wo16, out_sec,
                                      zbuf, Wo16, out_sec);
}

// Round 6
// 686.198 us; speedup vs baseline: 1.5043x; 1.0314x over previous
//
#include <hip/hip_runtime.h>
#include <math.h>

typedef unsigned short u16;
typedef __attribute__((ext_vector_type(8))) short short8;
typedef __attribute__((ext_vector_type(4))) float floatx4;
typedef __attribute__((ext_vector_type(4))) unsigned short ushort4v;

#define DEV static __device__ __forceinline__

DEV u16 f2b(float f) {
  unsigned u = __builtin_bit_cast(unsigned, f);
  u += 0x7fffu + ((u >> 16) & 1u);
  return (u16)(u >> 16);
}
DEV float b2f(u16 h) { return __builtin_bit_cast(float, ((unsigned)h) << 16); }

DEV void gld16(const u16* g, u16* l) {
  __builtin_amdgcn_global_load_lds((__attribute__((address_space(1))) void*)(g),
                                   (__attribute__((address_space(3))) void*)(l), 16, 0, 0);
}

// ---------------- K1: token-shift mixes -> 6 bf16 tensors ----------------
__global__ __launch_bounds__(256) void ew_mix(
    const float* __restrict__ x,
    const float* __restrict__ cr, const float* __restrict__ ck,
    const float* __restrict__ cv, const float* __restrict__ cw,
    const float* __restrict__ ca, const float* __restrict__ cg,
    u16* __restrict__ oxr, u16* __restrict__ oxk, u16* __restrict__ oxv,
    u16* __restrict__ oxw, u16* __restrict__ oxa, u16* __restrict__ oxg)
{
  const long idx = (long)blockIdx.x * 256 + threadIdx.x;
  const long row = idx >> 9;
  const int c4 = (int)(idx & 511) << 2;
  const long off = (row << 11) + c4;
  const float4 xc = *(const float4*)(x + off);
  float4 xp = make_float4(0.f, 0.f, 0.f, 0.f);
  if ((row & 4095) != 0) xp = *(const float4*)(x + off - 2048);
  const float xx0 = xp.x - xc.x, xx1 = xp.y - xc.y, xx2 = xp.z - xc.z, xx3 = xp.w - xc.w;
#define EMIT(cp, op) { const float4 cf = *(const float4*)(cp + c4);            \
    ushort4v o = { f2b(xc.x + xx0*cf.x), f2b(xc.y + xx1*cf.y),                 \
                   f2b(xc.z + xx2*cf.z), f2b(xc.w + xx3*cf.w) };               \
    *(ushort4v*)(op + off) = o; }
  EMIT(cr, oxr); EMIT(ck, oxk); EMIT(cv, oxv);
  EMIT(cw, oxw); EMIT(ca, oxa); EMIT(cg, oxg);
#undef EMIT
}

// ---------------- K2: cast 4 big square weights f32 -> bf16 ----------------
__global__ __launch_bounds__(256) void cast_w4(
    const float* __restrict__ s0, const float* __restrict__ s1,
    const float* __restrict__ s2, const float* __restrict__ s3,
    u16* __restrict__ d0, u16* __restrict__ d1, u16* __restrict__ d2, u16* __restrict__ d3)
{
  const float* s; u16* d;
  switch (blockIdx.y) {
    case 0: s = s0; d = d0; break;
    case 1: s = s1; d = d1; break;
    case 2: s = s2; d = d2; break;
    default: s = s3; d = d3; break;
  }
  const long i = ((long)blockIdx.x * 256 + threadIdx.x) * 8;
  const float4 a = *(const float4*)(s + i);
  const float4 b = *(const float4*)(s + i + 4);
  ushort4v lo = { f2b(a.x), f2b(a.y), f2b(a.z), f2b(a.w) };
  ushort4v hi = { f2b(b.x), f2b(b.y), f2b(b.z), f2b(b.w) };
  *(ushort4v*)(d + i) = lo;
  *(ushort4v*)(d + i + 4) = hi;
}

// ---------------- K3: transpose (+zero-pad) LoRA weights -> bf16 [N][K] ----------------
__global__ __launch_bounds__(256) void transpose_small(
    const float* __restrict__ w1, const float* __restrict__ a1,
    const float* __restrict__ v1, const float* __restrict__ g1,
    const float* __restrict__ w2, const float* __restrict__ a2,
    const float* __restrict__ v2, const float* __restrict__ g2,
    u16* __restrict__ w1T, u16* __restrict__ a1T, u16* __restrict__ v1T,
    u16* __restrict__ g1T, u16* __restrict__ w2T, u16* __restrict__ a2T,
    u16* __restrict__ v2T, u16* __restrict__ g2T)
{
  const long idx = (long)blockIdx.x * 256 + threadIdx.x;
  const float* src; u16* dst; int sk, sn, dn, dk;
  switch (blockIdx.y) {
    case 0: src = w1; dst = w1T; sk = 2048; sn = 128; dn = 128;  dk = 2048; break;
    case 1: src = a1; dst = a1T; sk = 2048; sn = 128; dn = 128;  dk = 2048; break;
    case 2: src = v1; dst = v1T; sk = 2048; sn = 64;  dn = 128;  dk = 2048; break;
    case 3: src = g1; dst = g1T; sk = 2048; sn = 224; dn = 256;  dk = 2048; break;
    case 4: src = w2; dst = w2T; sk = 128;  sn = 2048; dn = 2048; dk = 128; break;
    case 5: src = a2; dst = a2T; sk = 128;  sn = 2048; dn = 2048; dk = 128; break;
    case 6: src = v2; dst = v2T; sk = 64;   sn = 2048; dn = 2048; dk = 128; break;
    default:src = g2; dst = g2T; sk = 224;  sn = 2048; dn = 2048; dk = 256; break;
  }
  const long total = (long)dn * dk;
  if (idx >= total) return;
  const int n = (int)(idx / dk), k = (int)(idx % dk);
  float v = 0.f;
  if (k < sk && n < sn) v = src[(long)k * sn + n];
  dst[idx] = f2b(v);
}

// ---------------- shared 128x128 GEMM body (m97 structure) ----------------
#define GEMM128_BODY(Abase, Bbase, K)                                          \
  floatx4 acc[4][4];                                                           \
  _Pragma("unroll")                                                            \
  for (int i = 0; i < 4; ++i)                                                  \
    _Pragma("unroll")                                                          \
    for (int jq = 0; jq < 4; ++jq) acc[i][jq] = (floatx4)0.f;                  \
  const int nK = (K) >> 6;                                                     \
  for (int kt = 0; kt < nK; ++kt) {                                            \
    const int k0 = kt << 6;                                                    \
    __syncthreads();                                                           \
    _Pragma("unroll")                                                          \
    for (int i = 0; i < 4; ++i) {                                              \
      const int c = i * 256 + tid;                                             \
      const int row = c >> 3;                                                  \
      const int sch = (c & 7) ^ (row & 7);                                     \
      const long goff = (long)row * (K) + k0 + sch * 8;                        \
      const int lbase = (i * 256 + wave * 64) * 8;                             \
      gld16((Abase) + goff, &sA[lbase]);                                       \
      gld16((Bbase) + goff, &sB[lbase]);                                       \
    }                                                                          \
    asm volatile("s_waitcnt vmcnt(0)" ::: "memory");                           \
    __syncthreads();                                                           \
    _Pragma("unroll")                                                          \
    for (int ks = 0; ks < 2; ++ks) {                                           \
      short8 af[4], bfr[4];                                                    \
      _Pragma("unroll")                                                        \
      for (int mi = 0; mi < 4; ++mi) {                                         \
        const int row = wm * 64 + mi * 16 + lrow;                              \
        const int ch = (ks * 4 + lkg) ^ (row & 7);                             \
        af[mi] = *(const short8*)&sA[row * 64 + ch * 8];                       \
      }                                                                        \
      _Pragma("unroll")                                                        \
      for (int ni = 0; ni < 4; ++ni) {                                         \
        const int row = wn * 64 + ni * 16 + lrow;                              \
        const int ch = (ks * 4 + lkg) ^ (row & 7);                             \
        bfr[ni] = *(const short8*)&sB[row * 64 + ch * 8];                      \
      }                                                                        \
      _Pragma("unroll")                                                        \
      for (int mi = 0; mi < 4; ++mi)                                           \
        _Pragma("unroll")                                                      \
        for (int ni = 0; ni < 4; ++ni)                                         \
          acc[mi][ni] = __builtin_amdgcn_mfma_f32_16x16x32_bf16(af[mi], bfr[ni], acc[mi][ni], 0, 0, 0); \
    }                                                                          \
  }

// ---------------- merged LoRA stage-1: 4 jobs, one launch ----------------
__global__ __launch_bounds__(256, 2) void gemm_s1(
    const u16* __restrict__ xw, const u16* __restrict__ w1T, u16* __restrict__ hw,
    const u16* __restrict__ xa, const u16* __restrict__ a1T, u16* __restrict__ ha,
    const u16* __restrict__ xv, const u16* __restrict__ v1T, u16* __restrict__ hv,
    const u16* __restrict__ xg, const u16* __restrict__ g1T, u16* __restrict__ hg)
{
  __shared__ __align__(16) u16 sA[128 * 64];
  __shared__ __align__(16) u16 sB[128 * 64];
  const int bid = blockIdx.x;
  const int jid = (bid < 64) ? 0 : (bid < 128) ? 1 : (bid < 192) ? 2 : 3;
  const u16* A = (jid == 0) ? xw : (jid == 1) ? xa : (jid == 2) ? xv : xg;
  const u16* B = (jid == 0) ? w1T : (jid == 1) ? a1T : (jid == 2) ? v1T : g1T;
  u16* Cv = (jid == 0) ? hw : (jid == 1) ? ha : (jid == 2) ? hv : hg;
  const int N = (jid == 3) ? 256 : 128;
  const int lb = bid - ((jid == 0) ? 0 : (jid == 1) ? 64 : (jid == 2) ? 128 : 192);
  const int tid = threadIdx.x;
  const int wave = tid >> 6, lane = tid & 63;
  const int lrow = lane & 15, lkg = lane >> 4;
  const int wm = wave >> 1, wn = wave & 1;
  const int nbn = N >> 7;
  const int bm = lb / nbn, bn = lb % nbn;
  const u16* Abase = A + (long)bm * 128 * 2048;
  const u16* Bbase = B + (long)bn * 128 * 2048;

  GEMM128_BODY(Abase, Bbase, 2048)

  const int row0 = bm * 128 + wm * 64 + lkg * 4;
  const int col0 = bn * 128 + wn * 64 + lrow;
#pragma unroll
  for (int mi = 0; mi < 4; ++mi)
#pragma unroll
    for (int ni = 0; ni < 4; ++ni) {
      const int col = col0 + ni * 16;
#pragma unroll
      for (int r = 0; r < 4; ++r) {
        const long o = (long)(row0 + mi * 16 + r) * N + col;
        float v = acc[mi][ni][r];
        if (jid == 0) v = tanhf(v);
        else if (jid == 3) v = 1.f / (1.f + expf(-v));
        Cv[o] = f2b(v);
      }
    }
}

// ---------------- merged LoRA stage-2: 4 jobs x 1024 blocks ----------------
__global__ __launch_bounds__(256, 2) void gemm_s2(
    const u16* __restrict__ hw, const u16* __restrict__ w2T, float* __restrict__ wsec, const float* __restrict__ w0,
    const u16* __restrict__ ha, const u16* __restrict__ a2T, float* __restrict__ asec, const float* __restrict__ a0,
    const u16* __restrict__ hv, const u16* __restrict__ v2T, u16* __restrict__ vs, const float* __restrict__ v0,
    const u16* __restrict__ hg, const u16* __restrict__ g2T, u16* __restrict__ gb)
{
  __shared__ __align__(16) u16 sA[128 * 64];
  __shared__ __align__(16) u16 sB[128 * 64];
  const int jid = blockIdx.x >> 10;
  const int lb = blockIdx.x & 1023;
  const u16* A = (jid == 0) ? hw : (jid == 1) ? ha : (jid == 2) ? hv : hg;
  const u16* B = (jid == 0) ? w2T : (jid == 1) ? a2T : (jid == 2) ? v2T : g2T;
  const float* bias = (jid == 0) ? w0 : (jid == 1) ? a0 : v0;
  const int K = (jid == 3) ? 256 : 128;
  const int tid = threadIdx.x;
  const int wave = tid >> 6, lane = tid & 63;
  const int lrow = lane & 15, lkg = lane >> 4;
  const int wm = wave >> 1, wn = wave & 1;
  const int bm = lb >> 4, bn = lb & 15;   // N=2048 -> 16 bn
  const u16* Abase = A + (long)bm * 128 * K;
  const u16* Bbase = B + (long)bn * 128 * K;

  GEMM128_BODY(Abase, Bbase, K)

  const int row0 = bm * 128 + wm * 64 + lkg * 4;
  const int col0 = bn * 128 + wn * 64 + lrow;
#pragma unroll
  for (int mi = 0; mi < 4; ++mi)
#pragma unroll
    for (int ni = 0; ni < 4; ++ni) {
      const int col = col0 + ni * 16;
#pragma unroll
      for (int r = 0; r < 4; ++r) {
        const long o = (long)(row0 + mi * 16 + r) * 2048 + col;
        const float v = acc[mi][ni][r];
        if (jid == 0) {
          const float zz = -(v + bias[col]);
          const float sp = fmaxf(zz, 0.f) + log1pf(expf(-fabsf(zz)));
          wsec[o] = -sp - 0.5f;
        } else if (jid == 1) {
          asec[o] = 1.f / (1.f + expf(-(v + bias[col])));
        } else if (jid == 2) {
          vs[o] = f2b(1.f / (1.f + expf(-(v + bias[col]))));
        } else {
          gb[o] = f2b(v);
        }
      }
    }
}

// ---------------- GEMM 256x256 deep-pipelined (8-phase, counted vmcnt) ----------------
// XCD-aware swizzle: dispatch d -> XCD d&7 (round-robin); lb = (d&7)*32 + d>>3
// gives each XCD a contiguous 4bm x 8bn rectangle -> A panels 8-way shared,
// B panels 4-way shared within one XCD's L2 (T1).
template<int OP>  // 0=f32 out, 1=bf16 out
__global__ __launch_bounds__(512, 2) void gemm256(
    const u16* __restrict__ A0, const u16* __restrict__ B0, void* __restrict__ C0,
    const u16* __restrict__ A1, const u16* __restrict__ B1, void* __restrict__ C1,
    const u16* __restrict__ A2, const u16* __restrict__ B2, void* __restrict__ C2)
{
  __shared__ __align__(16) u16 lds[8 * 8192];
  const int tid = threadIdx.x;
  const int wave = tid >> 6, lane = tid & 63;
  const int lrow = lane & 15, lq = lane >> 4;
  const int wm = wave >> 2, wn = wave & 3;
  const int job = blockIdx.x >> 8;
  const int d = blockIdx.x & 255;
  const int lb = ((d & 7) << 5) | (d >> 3);   // bijective XCD swizzle
  const int bm = lb >> 3, bn = lb & 7;

  const u16* Aj = (job == 0) ? A0 : ((job == 1) ? A1 : A2);
  const u16* Bj = (job == 0) ? B0 : ((job == 1) ? B1 : B2);
  void* Cj      = (job == 0) ? C0 : ((job == 1) ? C1 : C2);

  const u16* __restrict__ Ab = Aj + (long)bm * 256 * 2048;
  const u16* __restrict__ Bb = Bj + (long)bn * 256 * 2048;

  int srco[2], dsto[2];
#pragma unroll
  for (int l = 0; l < 2; ++l) {
    const int c = l * 512 + tid;
    const int row = c >> 2, q = c & 3;
    const int qs = q ^ ((row >> 1) & 3);
    srco[l] = row * 2048 + qs * 8;
    dsto[l] = (l * 512 + wave * 64) * 8;
  }
  int offA[2][4], offB[4];
#pragma unroll
  for (int qm = 0; qm < 2; ++qm)
#pragma unroll
    for (int mi = 0; mi < 4; ++mi) {
      const int r = wm * 128 + qm * 64 + mi * 16 + lrow;
      offA[qm][mi] = r * 32 + (lq ^ ((r >> 1) & 3)) * 8;
    }
#pragma unroll
  for (int ni = 0; ni < 4; ++ni) {
    const int r = wn * 64 + ni * 16 + lrow;
    offB[ni] = r * 32 + (lq ^ ((r >> 1) & 3)) * 8;
  }

  floatx4 acc[8][4];
#pragma unroll
  for (int i = 0; i < 8; ++i)
#pragma unroll
    for (int jq = 0; jq < 4; ++jq) acc[i][jq] = (floatx4)0.f;

#define STAGE(sU, slot) {                                                  \
    const int t_ = (sU) >> 2, j_ = (sU) & 3;                               \
    const u16* base_ = (j_ & 1) ? Bb : Ab;                                 \
    const int kofs_ = t_ * 64 + ((j_ & 2) ? 32 : 0);                       \
    gld16(base_ + srco[0] + kofs_, &lds[(slot) * 8192 + dsto[0]]);         \
    gld16(base_ + srco[1] + kofs_, &lds[(slot) * 8192 + dsto[1]]);         \
  }

#pragma unroll
  for (int s = 0; s < 6; ++s) STAGE(s, s);
  asm volatile("s_waitcnt vmcnt(4)" ::: "memory");
  asm volatile("s_barrier" ::: "memory");

  short8 bfr[4];   // persists across the qm pair (read only on qm==0 phases)
  const int nT = 32;
  for (int te = 0; te < nT; te += 2) {
#pragma unroll
    for (int ph = 0; ph < 8; ++ph) {
      const int ks = (ph >> 1) & 1, qm = ph & 1;
      const int slotA = ((ph & 4) ? 4 : 0) + 2 * ks;
      const int slotB = slotA + 1;
      short8 af[4];
      if (qm == 0) {
#pragma unroll
        for (int ni = 0; ni < 4; ++ni)
          bfr[ni] = *(const short8*)&lds[slotB * 8192 + offB[ni]];
      }
#pragma unroll
      for (int mi = 0; mi < 4; ++mi)
        af[mi] = *(const short8*)&lds[slotA * 8192 + offA[qm][mi]];
      const int sU = 4 * te + 6 + ph;
      if (sU < 4 * nT) { STAGE(sU, (6 + ph) & 7); }
      if ((ph & 3) == 3) asm volatile("s_waitcnt vmcnt(4)" ::: "memory");
      asm volatile("s_barrier" ::: "memory");
      __builtin_amdgcn_s_setprio(1);
      const int am = qm * 4;
#pragma unroll
      for (int mi = 0; mi < 4; ++mi)
#pragma unroll
        for (int ni = 0; ni < 4; ++ni)
          acc[am + mi][ni] = __builtin_amdgcn_mfma_f32_16x16x32_bf16(af[mi], bfr[ni], acc[am + mi][ni], 0, 0, 0);
      __builtin_amdgcn_s_setprio(0);
      asm volatile("s_barrier" ::: "memory");
    }
  }
#undef STAGE

  const long row0 = (long)bm * 256 + wm * 128 + lq * 4;
  const int col0 = bn * 256 + wn * 64 + lrow;
#pragma unroll
  for (int mi = 0; mi < 8; ++mi) {
#pragma unroll
    for (int ni = 0; ni < 4; ++ni) {
      const int col = col0 + ni * 16;
#pragma unroll
      for (int r = 0; r < 4; ++r) {
        const long o = (row0 + mi * 16 + r) * 2048 + col;
        const float v = acc[mi][ni][r];
        if constexpr (OP == 0) ((float*)Cj)[o] = v;
        else ((u16*)Cj)[o] = f2b(v);
      }
    }
  }
}

// ---------------- K6: per-head fused epilogue (vectorized: 2 heads/wave, 2 ch/lane) ----------------
DEV float wsum32(float v) {
  v += __shfl_xor(v, 1);  v += __shfl_xor(v, 2);  v += __shfl_xor(v, 4);
  v += __shfl_xor(v, 8);  v += __shfl_xor(v, 16);
  return v;
}

__global__ __launch_bounds__(256) void ew_head(
    const u16* __restrict__ r16, const u16* __restrict__ k16,
    float* __restrict__ kkout,
    const float* __restrict__ abuf,
    const u16* __restrict__ v0buf, const u16* __restrict__ vsbuf,
    const u16* __restrict__ gbuf,
    const float* __restrict__ y, const float* __restrict__ vfirst,
    const float* __restrict__ kkc, const float* __restrict__ kac,
    const float* __restrict__ rk, const float* __restrict__ lng,
    const float* __restrict__ lnb, u16* __restrict__ z)
{
  const int tid = threadIdx.x;
  const int wave = tid >> 6, lane = tid & 63;
  const long php = (long)blockIdx.x * 4 + wave;   // head-pair id, 0..131071
  const long m = php >> 4;                         // token
  const int hp = (int)(php & 15);
  const int half = lane >> 5, li = lane & 31;
  const int c = hp * 128 + half * 64 + li * 2;     // even channel index
  const long off = (m << 11) + c;

  const unsigned k0p = *(const unsigned*)(k16 + off);
  const float k00 = b2f((u16)(k0p & 0xffff)), k01 = b2f((u16)(k0p >> 16));
  const float2 av = *(const float2*)(abuf + off);
  const float2 kkcv = *(const float2*)(kkc + c);
  const float2 kacv = *(const float2*)(kac + c);
  const float kf0 = k00 * (1.f + (av.x - 1.f) * kacv.x);
  const float kf1 = k01 * (1.f + (av.y - 1.f) * kacv.y);
  const float kr0 = k00 * kkcv.x, kr1 = k01 * kkcv.y;
  const float nrm = sqrtf(wsum32(kr0 * kr0 + kr1 * kr1));
  const float rn = 1.f / fmaxf(nrm, 1e-12f);
  *(float2*)(kkout + off) = make_float2(kr0 * rn, kr1 * rn);

  const float2 yv = *(const float2*)(y + off);
  const float mu = wsum32(yv.x + yv.y) * 0.015625f;
  const float dy0 = yv.x - mu, dy1 = yv.y - mu;
  const float var = wsum32(dy0 * dy0 + dy1 * dy1) * 0.015625f;
  const float rs = rsqrtf(var + 0.00064f);
  const float2 lngv = *(const float2*)(lng + c);
  const float2 lnbv = *(const float2*)(lnb + c);
  const float yn0 = dy0 * rs * lngv.x + lnbv.x;
  const float yn1 = dy1 * rs * lngv.y + lnbv.y;

  const unsigned rp = *(const unsigned*)(r16 + off);
  const float2 rkv = *(const float2*)(rk + c);
  const float dot = wsum32(b2f((u16)(rp & 0xffff)) * kf0 * rkv.x +
                           b2f((u16)(rp >> 16)) * kf1 * rkv.y);

  const unsigned v0p = *(const unsigned*)(v0buf + off);
  const unsigned vsp = *(const unsigned*)(vsbuf + off);
  const float2 vfv = *(const float2*)(vfirst + off);
  const float v00 = b2f((u16)(v0p & 0xffff)), v01 = b2f((u16)(v0p >> 16));
  const float sv0 = b2f((u16)(vsp & 0xffff)), sv1 = b2f((u16)(vsp >> 16));
  const float vv0 = v00 + (vfv.x - v00) * sv0;
  const float vv1 = v01 + (vfv.y - v01) * sv1;

  const unsigned gp = *(const unsigned*)(gbuf + off);
  const float z0 = (yn0 + dot * vv0) * b2f((u16)(gp & 0xffff));
  const float z1 = (yn1 + dot * vv1) * b2f((u16)(gp >> 16));
  *(unsigned*)(z + off) = (unsigned)f2b(z0) | ((unsigned)f2b(z1) << 16);
}

// ---------------- launch ----------------
extern "C" void kernel_launch(void* const* d_in, const int* in_sizes, int n_in,
                              void* d_out, int out_size, void* d_ws, size_t ws_size,
                              hipStream_t stream)
{
  (void)in_sizes; (void)out_size;
  if (n_in < 29) return;
  const int Mrows = 8192;
  const long C = 2048;
  const long MB_ = (long)Mrows * C;

  const float* x   = (const float*)d_in[0];
  const float* vf  = (const float*)d_in[1];
  const float* y   = (const float*)d_in[2];
  const float* x_r = (const float*)d_in[3];
  const float* x_w = (const float*)d_in[4];
  const float* x_k = (const float*)d_in[5];
  const float* x_v = (const float*)d_in[6];
  const float* x_a = (const float*)d_in[7];
  const float* x_g = (const float*)d_in[8];
  const float* w0  = (const float*)d_in[9];
  const float* w1  = (const float*)d_in[10];
  const float* w2  = (const float*)d_in[11];
  const float* a0  = (const float*)d_in[12];
  const float* a1  = (const float*)d_in[13];
  const float* a2  = (const float*)d_in[14];
  const float* v0  = (const float*)d_in[15];
  const float* v1  = (const float*)d_in[16];
  const float* v2  = (const float*)d_in[17];
  const float* g1  = (const float*)d_in[18];
  const float* g2  = (const float*)d_in[19];
  const float* k_k = (const float*)d_in[20];
  const float* k_a = (const float*)d_in[21];
  const float* r_k = (const float*)d_in[22];
  const float* W_r = (const float*)d_in[23];
  const float* W_k = (const float*)d_in[24];
  const float* W_v = (const float*)d_in[25];
  const float* W_o = (const float*)d_in[26];
  const float* lng = (const float*)d_in[27];
  const float* lnb = (const float*)d_in[28];

  float* out_sec = (float*)d_out;
  float* w_sec   = out_sec + MB_;
  float* a_sec   = w_sec + MB_;
  float* kk_sec  = a_sec + MB_;

  u16* k16 = (u16*)out_sec;            // dead d_out regions until final GEMM
  u16* r16 = (u16*)out_sec + MB_;
  u16* Wr16 = (u16*)w_sec;             // weight casts; dead before stage-2 writes w_sec
  u16* Wk16 = Wr16 + C * C;
  u16* Wv16 = Wk16 + C * C;

  u16* p = (u16*)d_ws;
  u16* xr = p;            p += MB_;
  u16* xk = p;            p += MB_;   // later z
  u16* xv = p;            p += MB_;
  u16* xw = p;            p += MB_;   // later vs
  u16* xa = p;            p += MB_;   // later g
  u16* xg = p;            p += MB_;   // later v0
  u16* Wo16 = p;          p += C * C;
  u16* w1T = p;           p += 128 * C;
  u16* a1T = p;           p += 128 * C;
  u16* v1T = p;           p += 128 * C;
  u16* g1T = p;           p += 256 * C;
  u16* w2T = p;           p += C * 128;
  u16* a2T = p;           p += C * 128;
  u16* v2T = p;           p += C * 128;
  u16* g2T = p;           p += C * 256;
  u16* hw  = p;           p += (long)Mrows * 128;
  u16* ha  = p;           p += (long)Mrows * 128;
  u16* hv  = p;           p += (long)Mrows * 128;
  u16* hg  = p;           p += (long)Mrows * 256;
  const size_t need = (size_t)((char*)p - (char*)d_ws);
  if (ws_size < need) return;

  u16* v0buf = xg;   // xg dead after gemm_s1; written by gemm256 job 2
  u16* zbuf  = xk;   // xk dead after gemm256 reads it
  u16* vsbuf = xw;   // xw dead after gemm_s1
  u16* gbuf  = xa;   // xa dead after gemm_s1

  // 1: mixes
  ew_mix<<<16384, 256, 0, stream>>>(x, x_r, x_k, x_v, x_w, x_a, x_g,
                                    xr, xk, xv, xw, xa, xg);
  // 2: big weight casts
  cast_w4<<<dim3(2048, 4), 256, 0, stream>>>(W_r, W_k, W_v, W_o, Wr16, Wk16, Wv16, Wo16);
  // 3: LoRA weight transposes (+zero pad)
  transpose_small<<<dim3(2048, 8), 256, 0, stream>>>(
      w1, a1, v1, g1, w2, a2, v2, g2,
      w1T, a1T, v1T, g1T, w2T, a2T, v2T, g2T);
  // 4: LoRA stage-1 (one 320-block launch)
  gemm_s1<<<320, 256, 0, stream>>>(xw, w1T, hw, xa, a1T, ha,
                                   xv, v1T, hv, xg, g1T, hg);
  // 5: r,k,v projections (one 768-block 256^2 pipelined launch)
  gemm256<1><<<768, 512, 0, stream>>>(xr, Wr16, r16,
                                      xk, Wk16, k16,
                                      xv, Wv16, v0buf);
  // 6: LoRA stage-2 (one 4096-block launch; w-job overwrites weight casts -> after 5)
  gemm_s2<<<4096, 256, 0, stream>>>(hw, w2T, w_sec, w0,
                                    ha, a2T, a_sec, a0,
                                    hv, v2T, vsbuf, v0,
                                    hg, g2T, gbuf);
  // 7: fused per-head epilogue -> kk + z (vectorized)
  ew_head<<<32768, 256, 0, stream>>>(r16, k16, kk_sec, a_sec, v0buf, vsbuf, gbuf,
                                     y, vf, k_k, k_a, r_k, lng, lnb, zbuf);
  // 8: final projection (overwrites out_sec; r16/k16 dead)
  gemm256<0><<<256, 512, 0, stream>>>(zbuf, Wo16, out_sec,
                                      zbuf, Wo16, out_sec,
                                      zbuf, Wo16, out_sec);
}

// Round 7
// 679.184 us; speedup vs baseline: 1.5198x; 1.0103x over previous
//
#include <hip/hip_runtime.h>
#include <math.h>

typedef unsigned short u16;
typedef __attribute__((ext_vector_type(8))) short short8;
typedef __attribute__((ext_vector_type(4))) float floatx4;
typedef __attribute__((ext_vector_type(4))) unsigned short ushort4v;

#define DEV static __device__ __forceinline__

DEV u16 f2b(float f) {
  unsigned u = __builtin_bit_cast(unsigned, f);
  u += 0x7fffu + ((u >> 16) & 1u);
  return (u16)(u >> 16);
}
DEV float b2f(u16 h) { return __builtin_bit_cast(float, ((unsigned)h) << 16); }

DEV void gld16(const u16* g, u16* l) {
  __builtin_amdgcn_global_load_lds((__attribute__((address_space(1))) void*)(g),
                                   (__attribute__((address_space(3))) void*)(l), 16, 0, 0);
}

// ---------------- K1: token-shift mixes -> 6 bf16 tensors ----------------
__global__ __launch_bounds__(256) void ew_mix(
    const float* __restrict__ x,
    const float* __restrict__ cr, const float* __restrict__ ck,
    const float* __restrict__ cv, const float* __restrict__ cw,
    const float* __restrict__ ca, const float* __restrict__ cg,
    u16* __restrict__ oxr, u16* __restrict__ oxk, u16* __restrict__ oxv,
    u16* __restrict__ oxw, u16* __restrict__ oxa, u16* __restrict__ oxg)
{
  const long idx = (long)blockIdx.x * 256 + threadIdx.x;
  const long row = idx >> 9;
  const int c4 = (int)(idx & 511) << 2;
  const long off = (row << 11) + c4;
  const float4 xc = *(const float4*)(x + off);
  float4 xp = make_float4(0.f, 0.f, 0.f, 0.f);
  if ((row & 4095) != 0) xp = *(const float4*)(x + off - 2048);
  const float xx0 = xp.x - xc.x, xx1 = xp.y - xc.y, xx2 = xp.z - xc.z, xx3 = xp.w - xc.w;
#define EMIT(cp, op) { const float4 cf = *(const float4*)(cp + c4);            \
    ushort4v o = { f2b(xc.x + xx0*cf.x), f2b(xc.y + xx1*cf.y),                 \
                   f2b(xc.z + xx2*cf.z), f2b(xc.w + xx3*cf.w) };               \
    *(ushort4v*)(op + off) = o; }
  EMIT(cr, oxr); EMIT(ck, oxk); EMIT(cv, oxv);
  EMIT(cw, oxw); EMIT(ca, oxa); EMIT(cg, oxg);
#undef EMIT
}

// ---------------- K2: cast 4 big square weights f32 -> bf16 ----------------
__global__ __launch_bounds__(256) void cast_w4(
    const float* __restrict__ s0, const float* __restrict__ s1,
    const float* __restrict__ s2, const float* __restrict__ s3,
    u16* __restrict__ d0, u16* __restrict__ d1, u16* __restrict__ d2, u16* __restrict__ d3)
{
  const float* s; u16* d;
  switch (blockIdx.y) {
    case 0: s = s0; d = d0; break;
    case 1: s = s1; d = d1; break;
    case 2: s = s2; d = d2; break;
    default: s = s3; d = d3; break;
  }
  const long i = ((long)blockIdx.x * 256 + threadIdx.x) * 8;
  const float4 a = *(const float4*)(s + i);
  const float4 b = *(const float4*)(s + i + 4);
  ushort4v lo = { f2b(a.x), f2b(a.y), f2b(a.z), f2b(a.w) };
  ushort4v hi = { f2b(b.x), f2b(b.y), f2b(b.z), f2b(b.w) };
  *(ushort4v*)(d + i) = lo;
  *(ushort4v*)(d + i + 4) = hi;
}

// ---------------- K3: transpose (+zero-pad) LoRA weights -> bf16 [N][K] ----------------
__global__ __launch_bounds__(256) void transpose_small(
    const float* __restrict__ w1, const float* __restrict__ a1,
    const float* __restrict__ v1, const float* __restrict__ g1,
    const float* __restrict__ w2, const float* __restrict__ a2,
    const float* __restrict__ v2, const float* __restrict__ g2,
    u16* __restrict__ w1T, u16* __restrict__ a1T, u16* __restrict__ v1T,
    u16* __restrict__ g1T, u16* __restrict__ w2T, u16* __restrict__ a2T,
    u16* __restrict__ v2T, u16* __restrict__ g2T)
{
  const long idx = (long)blockIdx.x * 256 + threadIdx.x;
  const float* src; u16* dst; int sk, sn, dn, dk;
  switch (blockIdx.y) {
    case 0: src = w1; dst = w1T; sk = 2048; sn = 128; dn = 128;  dk = 2048; break;
    case 1: src = a1; dst = a1T; sk = 2048; sn = 128; dn = 128;  dk = 2048; break;
    case 2: src = v1; dst = v1T; sk = 2048; sn = 64;  dn = 128;  dk = 2048; break;
    case 3: src = g1; dst = g1T; sk = 2048; sn = 224; dn = 256;  dk = 2048; break;
    case 4: src = w2; dst = w2T; sk = 128;  sn = 2048; dn = 2048; dk = 128; break;
    case 5: src = a2; dst = a2T; sk = 128;  sn = 2048; dn = 2048; dk = 128; break;
    case 6: src = v2; dst = v2T; sk = 64;   sn = 2048; dn = 2048; dk = 128; break;
    default:src = g2; dst = g2T; sk = 224;  sn = 2048; dn = 2048; dk = 256; break;
  }
  const long total = (long)dn * dk;
  if (idx >= total) return;
  const int n = (int)(idx / dk), k = (int)(idx % dk);
  float v = 0.f;
  if (k < sk && n < sn) v = src[(long)k * sn + n];
  dst[idx] = f2b(v);
}

// ---------------- shared 128x128 GEMM body (m97 structure) ----------------
#define GEMM128_BODY(Abase, Bbase, K)                                          \
  floatx4 acc[4][4];                                                           \
  _Pragma("unroll")                                                            \
  for (int i = 0; i < 4; ++i)                                                  \
    _Pragma("unroll")                                                          \
    for (int jq = 0; jq < 4; ++jq) acc[i][jq] = (floatx4)0.f;                  \
  const int nK = (K) >> 6;                                                     \
  for (int kt = 0; kt < nK; ++kt) {                                            \
    const int k0 = kt << 6;                                                    \
    __syncthreads();                                                           \
    _Pragma("unroll")                                                          \
    for (int i = 0; i < 4; ++i) {                                              \
      const int c = i * 256 + tid;                                             \
      const int row = c >> 3;                                                  \
      const int sch = (c & 7) ^ (row & 7);                                     \
      const long goff = (long)row * (K) + k0 + sch * 8;                        \
      const int lbase = (i * 256 + wave * 64) * 8;                             \
      gld16((Abase) + goff, &sA[lbase]);                                       \
      gld16((Bbase) + goff, &sB[lbase]);                                       \
    }                                                                          \
    asm volatile("s_waitcnt vmcnt(0)" ::: "memory");                           \
    __syncthreads();                                                           \
    _Pragma("unroll")                                                          \
    for (int ks = 0; ks < 2; ++ks) {                                           \
      short8 af[4], bfr[4];                                                    \
      _Pragma("unroll")                                                        \
      for (int mi = 0; mi < 4; ++mi) {                                         \
        const int row = wm * 64 + mi * 16 + lrow;                              \
        const int ch = (ks * 4 + lkg) ^ (row & 7);                             \
        af[mi] = *(const short8*)&sA[row * 64 + ch * 8];                       \
      }                                                                        \
      _Pragma("unroll")                                                        \
      for (int ni = 0; ni < 4; ++ni) {                                         \
        const int row = wn * 64 + ni * 16 + lrow;                              \
        const int ch = (ks * 4 + lkg) ^ (row & 7);                             \
        bfr[ni] = *(const short8*)&sB[row * 64 + ch * 8];                      \
      }                                                                        \
      _Pragma("unroll")                                                        \
      for (int mi = 0; mi < 4; ++mi)                                           \
        _Pragma("unroll")                                                      \
        for (int ni = 0; ni < 4; ++ni)                                         \
          acc[mi][ni] = __builtin_amdgcn_mfma_f32_16x16x32_bf16(af[mi], bfr[ni], acc[mi][ni], 0, 0, 0); \
    }                                                                          \
  }

// ---------------- merged LoRA stage-1: 4 jobs, one launch ----------------
__global__ __launch_bounds__(256, 2) void gemm_s1(
    const u16* __restrict__ xw, const u16* __restrict__ w1T, u16* __restrict__ hw,
    const u16* __restrict__ xa, const u16* __restrict__ a1T, u16* __restrict__ ha,
    const u16* __restrict__ xv, const u16* __restrict__ v1T, u16* __restrict__ hv,
    const u16* __restrict__ xg, const u16* __restrict__ g1T, u16* __restrict__ hg)
{
  __shared__ __align__(16) u16 sA[128 * 64];
  __shared__ __align__(16) u16 sB[128 * 64];
  const int bid = blockIdx.x;
  const int jid = (bid < 64) ? 0 : (bid < 128) ? 1 : (bid < 192) ? 2 : 3;
  const u16* A = (jid == 0) ? xw : (jid == 1) ? xa : (jid == 2) ? xv : xg;
  const u16* B = (jid == 0) ? w1T : (jid == 1) ? a1T : (jid == 2) ? v1T : g1T;
  u16* Cv = (jid == 0) ? hw : (jid == 1) ? ha : (jid == 2) ? hv : hg;
  const int N = (jid == 3) ? 256 : 128;
  const int lb = bid - ((jid == 0) ? 0 : (jid == 1) ? 64 : (jid == 2) ? 128 : 192);
  const int tid = threadIdx.x;
  const int wave = tid >> 6, lane = tid & 63;
  const int lrow = lane & 15, lkg = lane >> 4;
  const int wm = wave >> 1, wn = wave & 1;
  const int nbn = N >> 7;
  const int bm = lb / nbn, bn = lb % nbn;
  const u16* Abase = A + (long)bm * 128 * 2048;
  const u16* Bbase = B + (long)bn * 128 * 2048;

  GEMM128_BODY(Abase, Bbase, 2048)

  const int row0 = bm * 128 + wm * 64 + lkg * 4;
  const int col0 = bn * 128 + wn * 64 + lrow;
#pragma unroll
  for (int mi = 0; mi < 4; ++mi)
#pragma unroll
    for (int ni = 0; ni < 4; ++ni) {
      const int col = col0 + ni * 16;
#pragma unroll
      for (int r = 0; r < 4; ++r) {
        const long o = (long)(row0 + mi * 16 + r) * N + col;
        float v = acc[mi][ni][r];
        if (jid == 0) v = tanhf(v);
        else if (jid == 3) v = 1.f / (1.f + expf(-v));
        Cv[o] = f2b(v);
      }
    }
}

// ---------------- merged LoRA stage-2: 4 jobs x 1024 blocks ----------------
__global__ __launch_bounds__(256, 2) void gemm_s2(
    const u16* __restrict__ hw, const u16* __restrict__ w2T, float* __restrict__ wsec, const float* __restrict__ w0,
    const u16* __restrict__ ha, const u16* __restrict__ a2T, float* __restrict__ asec, const float* __restrict__ a0,
    const u16* __restrict__ hv, const u16* __restrict__ v2T, u16* __restrict__ vs, const float* __restrict__ v0,
    const u16* __restrict__ hg, const u16* __restrict__ g2T, u16* __restrict__ gb)
{
  __shared__ __align__(16) u16 sA[128 * 64];
  __shared__ __align__(16) u16 sB[128 * 64];
  const int jid = blockIdx.x >> 10;
  const int lb = blockIdx.x & 1023;
  const u16* A = (jid == 0) ? hw : (jid == 1) ? ha : (jid == 2) ? hv : hg;
  const u16* B = (jid == 0) ? w2T : (jid == 1) ? a2T : (jid == 2) ? v2T : g2T;
  const float* bias = (jid == 0) ? w0 : (jid == 1) ? a0 : v0;
  const int K = (jid == 3) ? 256 : 128;
  const int tid = threadIdx.x;
  const int wave = tid >> 6, lane = tid & 63;
  const int lrow = lane & 15, lkg = lane >> 4;
  const int wm = wave >> 1, wn = wave & 1;
  const int bm = lb >> 4, bn = lb & 15;   // N=2048 -> 16 bn
  const u16* Abase = A + (long)bm * 128 * K;
  const u16* Bbase = B + (long)bn * 128 * K;

  GEMM128_BODY(Abase, Bbase, K)

  const int row0 = bm * 128 + wm * 64 + lkg * 4;
  const int col0 = bn * 128 + wn * 64 + lrow;
#pragma unroll
  for (int mi = 0; mi < 4; ++mi)
#pragma unroll
    for (int ni = 0; ni < 4; ++ni) {
      const int col = col0 + ni * 16;
#pragma unroll
      for (int r = 0; r < 4; ++r) {
        const long o = (long)(row0 + mi * 16 + r) * 2048 + col;
        const float v = acc[mi][ni][r];
        if (jid == 0) {
          const float zz = -(v + bias[col]);
          const float sp = fmaxf(zz, 0.f) + log1pf(expf(-fabsf(zz)));
          wsec[o] = -sp - 0.5f;
        } else if (jid == 1) {
          asec[o] = 1.f / (1.f + expf(-(v + bias[col])));
        } else if (jid == 2) {
          vs[o] = f2b(1.f / (1.f + expf(-(v + bias[col]))));
        } else {
          gb[o] = f2b(v);
        }
      }
    }
}

// ---------------- GEMM 256x256 deep-pipelined (8-phase, counted vmcnt) ----------------
// Single barrier per phase (at phase start). Ledger: phase n reads units
// {n&~1,n|1}; STAGE at n overwrites unit n-2 whose last read (phase n-1)
// drains before each wave's phase-(n-1) MFMA, hence before barrier-n, hence
// before any STAGE-n issue (WAR safe). vmcnt(4) at n%4==3 runs per-wave
// BEFORE the next barrier, so after that barrier all waves' units <= n+3
// have landed collectively (RAW safe).
template<int OP>  // 0=f32 out, 1=bf16 out
__global__ __launch_bounds__(512, 2) void gemm256(
    const u16* __restrict__ A0, const u16* __restrict__ B0, void* __restrict__ C0,
    const u16* __restrict__ A1, const u16* __restrict__ B1, void* __restrict__ C1,
    const u16* __restrict__ A2, const u16* __restrict__ B2, void* __restrict__ C2)
{
  __shared__ __align__(16) u16 lds[8 * 8192];
  const int tid = threadIdx.x;
  const int wave = tid >> 6, lane = tid & 63;
  const int lrow = lane & 15, lq = lane >> 4;
  const int wm = wave >> 2, wn = wave & 3;
  const int job = blockIdx.x >> 8;
  const int d = blockIdx.x & 255;
  const int lb = ((d & 7) << 5) | (d >> 3);   // bijective XCD swizzle
  const int bm = lb >> 3, bn = lb & 7;

  const u16* Aj = (job == 0) ? A0 : ((job == 1) ? A1 : A2);
  const u16* Bj = (job == 0) ? B0 : ((job == 1) ? B1 : B2);
  void* Cj      = (job == 0) ? C0 : ((job == 1) ? C1 : C2);

  const u16* __restrict__ Ab = Aj + (long)bm * 256 * 2048;
  const u16* __restrict__ Bb = Bj + (long)bn * 256 * 2048;

  int srco[2], dsto[2];
#pragma unroll
  for (int l = 0; l < 2; ++l) {
    const int c = l * 512 + tid;
    const int row = c >> 2, q = c & 3;
    const int qs = q ^ ((row >> 1) & 3);
    srco[l] = row * 2048 + qs * 8;
    dsto[l] = (l * 512 + wave * 64) * 8;
  }
  int offA[2][4], offB[4];
#pragma unroll
  for (int qm = 0; qm < 2; ++qm)
#pragma unroll
    for (int mi = 0; mi < 4; ++mi) {
      const int r = wm * 128 + qm * 64 + mi * 16 + lrow;
      offA[qm][mi] = r * 32 + (lq ^ ((r >> 1) & 3)) * 8;
    }
#pragma unroll
  for (int ni = 0; ni < 4; ++ni) {
    const int r = wn * 64 + ni * 16 + lrow;
    offB[ni] = r * 32 + (lq ^ ((r >> 1) & 3)) * 8;
  }

  floatx4 acc[8][4];
#pragma unroll
  for (int i = 0; i < 8; ++i)
#pragma unroll
    for (int jq = 0; jq < 4; ++jq) acc[i][jq] = (floatx4)0.f;

#define STAGE(sU, slot) {                                                  \
    const int t_ = (sU) >> 2, j_ = (sU) & 3;                               \
    const u16* base_ = (j_ & 1) ? Bb : Ab;                                 \
    const int kofs_ = t_ * 64 + ((j_ & 2) ? 32 : 0);                       \
    gld16(base_ + srco[0] + kofs_, &lds[(slot) * 8192 + dsto[0]]);         \
    gld16(base_ + srco[1] + kofs_, &lds[(slot) * 8192 + dsto[1]]);         \
  }

#pragma unroll
  for (int s = 0; s < 6; ++s) STAGE(s, s);
  asm volatile("s_waitcnt vmcnt(4)" ::: "memory");
  // barrier moved to loop head (one barrier per phase)

  short8 bfr[4];   // persists across the qm pair (read only on qm==0 phases)
  const int nT = 32;
  for (int te = 0; te < nT; te += 2) {
#pragma unroll
    for (int ph = 0; ph < 8; ++ph) {
      const int ks = (ph >> 1) & 1, qm = ph & 1;
      const int slotA = ((ph & 4) ? 4 : 0) + 2 * ks;
      const int slotB = slotA + 1;
      asm volatile("s_barrier" ::: "memory");
      short8 af[4];
      if (qm == 0) {
#pragma unroll
        for (int ni = 0; ni < 4; ++ni)
          bfr[ni] = *(const short8*)&lds[slotB * 8192 + offB[ni]];
      }
#pragma unroll
      for (int mi = 0; mi < 4; ++mi)
        af[mi] = *(const short8*)&lds[slotA * 8192 + offA[qm][mi]];
      const int sU = 4 * te + 6 + ph;
      if (sU < 4 * nT) { STAGE(sU, (6 + ph) & 7); }
      if ((ph & 3) == 3) asm volatile("s_waitcnt vmcnt(4)" ::: "memory");
      __builtin_amdgcn_s_setprio(1);
      const int am = qm * 4;
#pragma unroll
      for (int mi = 0; mi < 4; ++mi)
#pragma unroll
        for (int ni = 0; ni < 4; ++ni)
          acc[am + mi][ni] = __builtin_amdgcn_mfma_f32_16x16x32_bf16(af[mi], bfr[ni], acc[am + mi][ni], 0, 0, 0);
      __builtin_amdgcn_s_setprio(0);
    }
  }
#undef STAGE

  const long row0 = (long)bm * 256 + wm * 128 + lq * 4;
  const int col0 = bn * 256 + wn * 64 + lrow;
#pragma unroll
  for (int mi = 0; mi < 8; ++mi) {
#pragma unroll
    for (int ni = 0; ni < 4; ++ni) {
      const int col = col0 + ni * 16;
#pragma unroll
      for (int r = 0; r < 4; ++r) {
        const long o = (row0 + mi * 16 + r) * 2048 + col;
        const float v = acc[mi][ni][r];
        if constexpr (OP == 0) ((float*)Cj)[o] = v;
        else ((u16*)Cj)[o] = f2b(v);
      }
    }
  }
}

// ---------------- K6: per-head fused epilogue (2 heads/wave, 2 ch/lane) ----------------
DEV float wsum32(float v) {
  v += __shfl_xor(v, 1);  v += __shfl_xor(v, 2);  v += __shfl_xor(v, 4);
  v += __shfl_xor(v, 8);  v += __shfl_xor(v, 16);
  return v;
}

__global__ __launch_bounds__(256) void ew_head(
    const u16* __restrict__ r16, const u16* __restrict__ k16,
    float* __restrict__ kkout,
    const float* __restrict__ abuf,
    const u16* __restrict__ v0buf, const u16* __restrict__ vsbuf,
    const u16* __restrict__ gbuf,
    const float* __restrict__ y, const float* __restrict__ vfirst,
    const float* __restrict__ kkc, const float* __restrict__ kac,
    const float* __restrict__ rk, const float* __restrict__ lng,
    const float* __restrict__ lnb, u16* __restrict__ z)
{
  const int tid = threadIdx.x;
  const int wave = tid >> 6, lane = tid & 63;
  const long php = (long)blockIdx.x * 4 + wave;   // head-pair id
  const long m = php >> 4;                         // token
  const int hp = (int)(php & 15);
  const int half = lane >> 5, li = lane & 31;
  const int c = hp * 128 + half * 64 + li * 2;
  const long off = (m << 11) + c;

  const unsigned k0p = *(const unsigned*)(k16 + off);
  const float k00 = b2f((u16)(k0p & 0xffff)), k01 = b2f((u16)(k0p >> 16));
  const float2 av = *(const float2*)(abuf + off);
  const float2 kkcv = *(const float2*)(kkc + c);
  const float2 kacv = *(const float2*)(kac + c);
  const float kf0 = k00 * (1.f + (av.x - 1.f) * kacv.x);
  const float kf1 = k01 * (1.f + (av.y - 1.f) * kacv.y);
  const float kr0 = k00 * kkcv.x, kr1 = k01 * kkcv.y;
  const float nrm = sqrtf(wsum32(kr0 * kr0 + kr1 * kr1));
  const float rn = 1.f / fmaxf(nrm, 1e-12f);
  *(float2*)(kkout + off) = make_float2(kr0 * rn, kr1 * rn);

  const float2 yv = *(const float2*)(y + off);
  const float mu = wsum32(yv.x + yv.y) * 0.015625f;
  const float dy0 = yv.x - mu, dy1 = yv.y - mu;
  const float var = wsum32(dy0 * dy0 + dy1 * dy1) * 0.015625f;
  const float rs = rsqrtf(var + 0.00064f);
  const float2 lngv = *(const float2*)(lng + c);
  const float2 lnbv = *(const float2*)(lnb + c);
  const float yn0 = dy0 * rs * lngv.x + lnbv.x;
  const float yn1 = dy1 * rs * lngv.y + lnbv.y;

  const unsigned rp = *(const unsigned*)(r16 + off);
  const float2 rkv = *(const float2*)(rk + c);
  const float dot = wsum32(b2f((u16)(rp & 0xffff)) * kf0 * rkv.x +
                           b2f((u16)(rp >> 16)) * kf1 * rkv.y);

  const unsigned v0p = *(const unsigned*)(v0buf + off);
  const unsigned vsp = *(const unsigned*)(vsbuf + off);
  const float2 vfv = *(const float2*)(vfirst + off);
  const float v00 = b2f((u16)(v0p & 0xffff)), v01 = b2f((u16)(v0p >> 16));
  const float sv0 = b2f((u16)(vsp & 0xffff)), sv1 = b2f((u16)(vsp >> 16));
  const float vv0 = v00 + (vfv.x - v00) * sv0;
  const float vv1 = v01 + (vfv.y - v01) * sv1;

  const unsigned gp = *(const unsigned*)(gbuf + off);
  const float z0 = (yn0 + dot * vv0) * b2f((u16)(gp & 0xffff));
  const float z1 = (yn1 + dot * vv1) * b2f((u16)(gp >> 16));
  *(unsigned*)(z + off) = (unsigned)f2b(z0) | ((unsigned)f2b(z1) << 16);
}

// ---------------- launch ----------------
extern "C" void kernel_launch(void* const* d_in, const int* in_sizes, int n_in,
                              void* d_out, int out_size, void* d_ws, size_t ws_size,
                              hipStream_t stream)
{
  (void)in_sizes; (void)out_size;
  if (n_in < 29) return;
  const int Mrows = 8192;
  const long C = 2048;
  const long MB_ = (long)Mrows * C;

  const float* x   = (const float*)d_in[0];
  const float* vf  = (const float*)d_in[1];
  const float* y   = (const float*)d_in[2];
  const float* x_r = (const float*)d_in[3];
  const float* x_w = (const float*)d_in[4];
  const float* x_k = (const float*)d_in[5];
  const float* x_v = (const float*)d_in[6];
  const float* x_a = (const float*)d_in[7];
  const float* x_g = (const float*)d_in[8];
  const float* w0  = (const float*)d_in[9];
  const float* w1  = (const float*)d_in[10];
  const float* w2  = (const float*)d_in[11];
  const float* a0  = (const float*)d_in[12];
  const float* a1  = (const float*)d_in[13];
  const float* a2  = (const float*)d_in[14];
  const float* v0  = (const float*)d_in[15];
  const float* v1  = (const float*)d_in[16];
  const float* v2  = (const float*)d_in[17];
  const float* g1  = (const float*)d_in[18];
  const float* g2  = (const float*)d_in[19];
  const float* k_k = (const float*)d_in[20];
  const float* k_a = (const float*)d_in[21];
  const float* r_k = (const float*)d_in[22];
  const float* W_r = (const float*)d_in[23];
  const float* W_k = (const float*)d_in[24];
  const float* W_v = (const float*)d_in[25];
  const float* W_o = (const float*)d_in[26];
  const float* lng = (const float*)d_in[27];
  const float* lnb = (const float*)d_in[28];

  float* out_sec = (float*)d_out;
  float* w_sec   = out_sec + MB_;
  float* a_sec   = w_sec + MB_;
  float* kk_sec  = a_sec + MB_;

  u16* k16 = (u16*)out_sec;            // dead d_out regions until final GEMM
  u16* r16 = (u16*)out_sec + MB_;
  u16* Wr16 = (u16*)w_sec;             // weight casts; dead before stage-2 writes w_sec
  u16* Wk16 = Wr16 + C * C;
  u16* Wv16 = Wk16 + C * C;

  u16* p = (u16*)d_ws;
  u16* xr = p;            p += MB_;
  u16* xk = p;            p += MB_;   // later z
  u16* xv = p;            p += MB_;
  u16* xw = p;            p += MB_;   // later vs
  u16* xa = p;            p += MB_;   // later g
  u16* xg = p;            p += MB_;   // later v0
  u16* Wo16 = p;          p += C * C;
  u16* w1T = p;           p += 128 * C;
  u16* a1T = p;           p += 128 * C;
  u16* v1T = p;           p += 128 * C;
  u16* g1T = p;           p += 256 * C;
  u16* w2T = p;           p += C * 128;
  u16* a2T = p;           p += C * 128;
  u16* v2T = p;           p += C * 128;
  u16* g2T = p;           p += C * 256;
  u16* hw  = p;           p += (long)Mrows * 128;
  u16* ha  = p;           p += (long)Mrows * 128;
  u16* hv  = p;           p += (long)Mrows * 128;
  u16* hg  = p;           p += (long)Mrows * 256;
  const size_t need = (size_t)((char*)p - (char*)d_ws);
  if (ws_size < need) return;

  u16* v0buf = xg;   // xg dead after gemm_s1; written by gemm256 job 2
  u16* zbuf  = xk;   // xk dead after gemm256 reads it
  u16* vsbuf = xw;   // xw dead after gemm_s1
  u16* gbuf  = xa;   // xa dead after gemm_s1

  // 1: mixes
  ew_mix<<<16384, 256, 0, stream>>>(x, x_r, x_k, x_v, x_w, x_a, x_g,
                                    xr, xk, xv, xw, xa, xg);
  // 2: big weight casts
  cast_w4<<<dim3(2048, 4), 256, 0, stream>>>(W_r, W_k, W_v, W_o, Wr16, Wk16, Wv16, Wo16);
  // 3: LoRA weight transposes (+zero pad)
  transpose_small<<<dim3(2048, 8), 256, 0, stream>>>(
      w1, a1, v1, g1, w2, a2, v2, g2,
      w1T, a1T, v1T, g1T, w2T, a2T, v2T, g2T);
  // 4: LoRA stage-1 (one 320-block launch)
  gemm_s1<<<320, 256, 0, stream>>>(xw, w1T, hw, xa, a1T, ha,
                                   xv, v1T, hv, xg, g1T, hg);
  // 5: r,k,v projections (one 768-block 256^2 pipelined launch)
  gemm256<1><<<768, 512, 0, stream>>>(xr, Wr16, r16,
                                      xk, Wk16, k16,
                                      xv, Wv16, v0buf);
  // 6: LoRA stage-2 (one 4096-block launch; w-job overwrites weight casts -> after 5)
  gemm_s2<<<4096, 256, 0, stream>>>(hw, w2T, w_sec, w0,
                                    ha, a2T, a_sec, a0,
                                    hv, v2T, vsbuf, v0,
                                    hg, g2T, gbuf);
  // 7: fused per-head epilogue -> kk + z (vectorized)
  ew_head<<<32768, 256, 0, stream>>>(r16, k16, kk_sec, a_sec, v0buf, vsbuf, gbuf,
                                     y, vf, k_k, k_a, r_k, lng, lnb, zbuf);
  // 8: final projection (overwrites out_sec; r16/k16 dead)
  gemm256<0><<<256, 512, 0, stream>>>(zbuf, Wo16, out_sec,
                                      zbuf, Wo16, out_sec,
                                      zbuf, Wo16, out_sec);
}